// Round 2
// baseline (1994.568 us; speedup 1.0000x reference)
//
#include <hip/hip_runtime.h>
#include <math.h>

#define NA     4096
#define HIDDEN 1024
#define NHEADS 8
#define DH     128
#define LN_EPS 1e-5f
#define F_SCALE 1.0f

// ---- workspace layout (floats) ----
#define OFF_Q     0
#define OFF_K     (NA*HIDDEN)          // 4194304
#define OFF_V     (2*NA*HIDDEN)
#define OFF_RET   (3*NA*HIDDEN)
#define OFF_Y     OFF_Q                // Q dead after k_ret; reuse for Y
#define OFF_M     (4*NA*HIDDEN)        // 8*128*128
#define OFF_RMAXD (OFF_M + NHEADS*DH*DH)
#define OFF_RINVD (OFF_RMAXD + NA)
#define OFF_RMAXC (OFF_RINVD + NA)
#define OFF_RINVC (OFF_RMAXC + NA)

// =====================================================================
// Projections: Q/K/V = X @ {Wq,Wk,Wv}.  128x128 tile, BK=8, 8x8/thread.
// =====================================================================
__global__ __launch_bounds__(256) void k_proj(
    const float* __restrict__ X, const float* __restrict__ Wq,
    const float* __restrict__ Wk, const float* __restrict__ Wv,
    float* __restrict__ ws)
{
    __shared__ float As[8][132];
    __shared__ float Bs[8][132];
    const float* W = (blockIdx.z == 0) ? Wq : (blockIdx.z == 1) ? Wk : Wv;
    float* O = ws + ((blockIdx.z == 0) ? OFF_Q : (blockIdx.z == 1) ? OFF_K : OFF_V);

    const int tid = threadIdx.x;
    const int tx = tid & 15, ty = tid >> 4;
    const int row0 = blockIdx.y * 128, col0 = blockIdx.x * 128;
    const int arow = tid >> 1, ak = (tid & 1) * 4;   // A-tile: 128 rows x 8 k
    const int bk = tid >> 5, bc = (tid & 31) * 4;    // B-tile: 8 k x 128 cols

    float acc[8][8];
#pragma unroll
    for (int i = 0; i < 8; i++)
#pragma unroll
        for (int j = 0; j < 8; j++) acc[i][j] = 0.f;

    for (int kt = 0; kt < HIDDEN; kt += 8) {
        float4 av = *(const float4*)(X + (row0 + arow) * HIDDEN + kt + ak);
        float4 bv = *(const float4*)(W + (kt + bk) * HIDDEN + col0 + bc);
        __syncthreads();
        As[ak + 0][arow] = av.x; As[ak + 1][arow] = av.y;
        As[ak + 2][arow] = av.z; As[ak + 3][arow] = av.w;
        *(float4*)&Bs[bk][bc] = bv;
        __syncthreads();
#pragma unroll
        for (int k = 0; k < 8; k++) {
            float4 a0 = *(const float4*)&As[k][ty * 8];
            float4 a1 = *(const float4*)&As[k][ty * 8 + 4];
            float4 b0 = *(const float4*)&Bs[k][tx * 8];
            float4 b1 = *(const float4*)&Bs[k][tx * 8 + 4];
            float a[8] = {a0.x,a0.y,a0.z,a0.w,a1.x,a1.y,a1.z,a1.w};
            float b[8] = {b0.x,b0.y,b0.z,b0.w,b1.x,b1.y,b1.z,b1.w};
#pragma unroll
            for (int i = 0; i < 8; i++)
#pragma unroll
                for (int j = 0; j < 8; j++)
                    acc[i][j] = fmaf(a[i], b[j], acc[i][j]);
        }
    }
#pragma unroll
    for (int i = 0; i < 8; i++) {
        float* dst = O + (row0 + ty * 8 + i) * HIDDEN + col0 + tx * 8;
        *(float4*)dst       = make_float4(acc[i][0], acc[i][1], acc[i][2], acc[i][3]);
        *(float4*)(dst + 4) = make_float4(acc[i][4], acc[i][5], acc[i][6], acc[i][7]);
    }
}

// =====================================================================
// Row softmax stats for f_dist / f_clb: rmax[row], 1/sum(exp(x-rmax))
// =====================================================================
__global__ __launch_bounds__(256) void k_rowstats(
    const float* __restrict__ f_dist, const float* __restrict__ f_clb,
    float* __restrict__ ws)
{
    const int row = blockIdx.x, mat = blockIdx.y, t = threadIdx.x;
    const float* F = mat ? f_clb : f_dist;
    float* rmax = ws + (mat ? OFF_RMAXC : OFF_RMAXD);
    float* rinv = ws + (mat ? OFF_RINVC : OFF_RINVD);

    float4 v[4];
#pragma unroll
    for (int p = 0; p < 4; p++)
        v[p] = *(const float4*)(F + (size_t)row * NA + 4 * t + 1024 * p);

    float m = -1e30f;
#pragma unroll
    for (int p = 0; p < 4; p++) {
        m = fmaxf(m, fmaxf(fmaxf(v[p].x, v[p].y), fmaxf(v[p].z, v[p].w)));
    }
    for (int off = 32; off; off >>= 1) m = fmaxf(m, __shfl_xor(m, off));
    __shared__ float sb[4];
    if ((t & 63) == 0) sb[t >> 6] = m;
    __syncthreads();
    const float m4 = fmaxf(fmaxf(sb[0], sb[1]), fmaxf(sb[2], sb[3]));
    __syncthreads();

    float s = 0.f;
#pragma unroll
    for (int p = 0; p < 4; p++) {
        s += expf(v[p].x - m4) + expf(v[p].y - m4)
           + expf(v[p].z - m4) + expf(v[p].w - m4);
    }
    for (int off = 32; off; off >>= 1) s += __shfl_xor(s, off);
    if ((t & 63) == 0) sb[t >> 6] = s;
    __syncthreads();
    if (t == 0) {
        rmax[row] = m4;
        rinv[row] = 1.0f / (sb[0] + sb[1] + sb[2] + sb[3]);
    }
}

// =====================================================================
// M_h = k_h^T @ v_h  (8 x 128 x 128), split over 16 n-chunks, atomicAdd
// =====================================================================
__global__ __launch_bounds__(256) void k_ktv(float* __restrict__ ws)
{
    __shared__ float Ks[8][132];
    __shared__ float Vs[8][132];
    const float* Kp = ws + OFF_K;
    const float* Vp = ws + OFF_V;
    float* M = ws + OFF_M;

    const int h = blockIdx.y, ci = blockIdx.x;
    const int tid = threadIdx.x;
    const int tx = tid & 15, ty = tid >> 4;
    const int lr = tid >> 5, lc = (tid & 31) * 4;

    float acc[8][8];
#pragma unroll
    for (int i = 0; i < 8; i++)
#pragma unroll
        for (int j = 0; j < 8; j++) acc[i][j] = 0.f;

    for (int n0 = ci * 256; n0 < ci * 256 + 256; n0 += 8) {
        float4 kv = *(const float4*)(Kp + (n0 + lr) * HIDDEN + h * DH + lc);
        float4 vv = *(const float4*)(Vp + (n0 + lr) * HIDDEN + h * DH + lc);
        __syncthreads();
        *(float4*)&Ks[lr][lc] = kv;
        *(float4*)&Vs[lr][lc] = vv;
        __syncthreads();
#pragma unroll
        for (int n = 0; n < 8; n++) {
            float4 a0 = *(const float4*)&Ks[n][ty * 8];
            float4 a1 = *(const float4*)&Ks[n][ty * 8 + 4];
            float4 b0 = *(const float4*)&Vs[n][tx * 8];
            float4 b1 = *(const float4*)&Vs[n][tx * 8 + 4];
            float a[8] = {a0.x,a0.y,a0.z,a0.w,a1.x,a1.y,a1.z,a1.w};
            float b[8] = {b0.x,b0.y,b0.z,b0.w,b1.x,b1.y,b1.z,b1.w};
#pragma unroll
            for (int i = 0; i < 8; i++)
#pragma unroll
                for (int j = 0; j < 8; j++)
                    acc[i][j] = fmaf(a[i], b[j], acc[i][j]);
        }
    }
#pragma unroll
    for (int i = 0; i < 8; i++)
#pragma unroll
        for (int j = 0; j < 8; j++)
            atomicAdd(&M[h * DH * DH + (ty * 8 + i) * DH + tx * 8 + j], acc[i][j]);
}

// =====================================================================
// scores_mean = c/8*Q@K^T + c/4*F_SCALE*(adj + softmax(fd) + softmax(fc))
// NT GEMM over K=1024 with fused elementwise epilogue.
// =====================================================================
__global__ __launch_bounds__(256) void k_scores(
    const float* __restrict__ ws,
    const float* __restrict__ f_adj, const float* __restrict__ f_dist,
    const float* __restrict__ f_clb, float* __restrict__ out_scores,
    float cdiv8, float cdiv4)
{
    __shared__ float As[8][132];
    __shared__ float Bs[8][132];
    const float* Q = ws + OFF_Q;
    const float* K = ws + OFF_K;
    const float* rmaxd = ws + OFF_RMAXD, *rinvd = ws + OFF_RINVD;
    const float* rmaxc = ws + OFF_RMAXC, *rinvc = ws + OFF_RINVC;

    const int tid = threadIdx.x;
    const int tx = tid & 15, ty = tid >> 4;
    const int row0 = blockIdx.y * 128, col0 = blockIdx.x * 128;
    const int arow = tid >> 1, ak = (tid & 1) * 4;

    float acc[8][8];
#pragma unroll
    for (int i = 0; i < 8; i++)
#pragma unroll
        for (int j = 0; j < 8; j++) acc[i][j] = 0.f;

    for (int kt = 0; kt < HIDDEN; kt += 8) {
        float4 av = *(const float4*)(Q + (row0 + arow) * HIDDEN + kt + ak);
        float4 bv = *(const float4*)(K + (col0 + arow) * HIDDEN + kt + ak);
        __syncthreads();
        As[ak + 0][arow] = av.x; As[ak + 1][arow] = av.y;
        As[ak + 2][arow] = av.z; As[ak + 3][arow] = av.w;
        Bs[ak + 0][arow] = bv.x; Bs[ak + 1][arow] = bv.y;
        Bs[ak + 2][arow] = bv.z; Bs[ak + 3][arow] = bv.w;
        __syncthreads();
#pragma unroll
        for (int k = 0; k < 8; k++) {
            float4 a0 = *(const float4*)&As[k][ty * 8];
            float4 a1 = *(const float4*)&As[k][ty * 8 + 4];
            float4 b0 = *(const float4*)&Bs[k][tx * 8];
            float4 b1 = *(const float4*)&Bs[k][tx * 8 + 4];
            float a[8] = {a0.x,a0.y,a0.z,a0.w,a1.x,a1.y,a1.z,a1.w};
            float b[8] = {b0.x,b0.y,b0.z,b0.w,b1.x,b1.y,b1.z,b1.w};
#pragma unroll
            for (int i = 0; i < 8; i++)
#pragma unroll
                for (int j = 0; j < 8; j++)
                    acc[i][j] = fmaf(a[i], b[j], acc[i][j]);
        }
    }
#pragma unroll
    for (int i = 0; i < 8; i++) {
        const int r = row0 + ty * 8 + i;
        const int c = col0 + tx * 8;
        const float rmd = rmaxd[r], rid = rinvd[r];
        const float rmc = rmaxc[r], ric = rinvc[r];
        float4 aj0 = *(const float4*)(f_adj  + (size_t)r * NA + c);
        float4 aj1 = *(const float4*)(f_adj  + (size_t)r * NA + c + 4);
        float4 fd0 = *(const float4*)(f_dist + (size_t)r * NA + c);
        float4 fd1 = *(const float4*)(f_dist + (size_t)r * NA + c + 4);
        float4 fc0 = *(const float4*)(f_clb  + (size_t)r * NA + c);
        float4 fc1 = *(const float4*)(f_clb  + (size_t)r * NA + c + 4);
        float bias[8];
        bias[0] = aj0.x + expf(fd0.x - rmd) * rid + expf(fc0.x - rmc) * ric;
        bias[1] = aj0.y + expf(fd0.y - rmd) * rid + expf(fc0.y - rmc) * ric;
        bias[2] = aj0.z + expf(fd0.z - rmd) * rid + expf(fc0.z - rmc) * ric;
        bias[3] = aj0.w + expf(fd0.w - rmd) * rid + expf(fc0.w - rmc) * ric;
        bias[4] = aj1.x + expf(fd1.x - rmd) * rid + expf(fc1.x - rmc) * ric;
        bias[5] = aj1.y + expf(fd1.y - rmd) * rid + expf(fc1.y - rmc) * ric;
        bias[6] = aj1.z + expf(fd1.z - rmd) * rid + expf(fc1.z - rmc) * ric;
        bias[7] = aj1.w + expf(fd1.w - rmd) * rid + expf(fc1.w - rmc) * ric;
        float o[8];
#pragma unroll
        for (int j = 0; j < 8; j++)
            o[j] = cdiv8 * acc[i][j] + cdiv4 * F_SCALE * bias[j];
        float* dst = out_scores + (size_t)r * NA + c;
        *(float4*)dst       = make_float4(o[0], o[1], o[2], o[3]);
        *(float4*)(dst + 4) = make_float4(o[4], o[5], o[6], o[7]);
    }
}

// =====================================================================
// ret[:, h*128:(h+1)*128] = relu(c * (B_h @ v_h + q_h @ M_h))
//   h=0,1: B=adj ; h=2,3: B=softmax(f_dist) ; h=4,5: B=softmax(f_clb)
//   h=6,7: no bias term
// =====================================================================
__global__ __launch_bounds__(256) void k_ret(
    float* __restrict__ ws,
    const float* __restrict__ f_adj, const float* __restrict__ f_dist,
    const float* __restrict__ f_clb, float c_scale)
{
    __shared__ float As[8][132];
    __shared__ float Bs[8][132];
    const float* Q = ws + OFF_Q;
    const float* V = ws + OFF_V;
    const float* M = ws + OFF_M;
    float* RET = ws + OFF_RET;

    const int h = blockIdx.z;
    const int tid = threadIdx.x;
    const int tx = tid & 15, ty = tid >> 4;
    const int row0 = blockIdx.y * 128;
    const int arow = tid >> 1, ak = (tid & 1) * 4;
    const int bk = tid >> 5, bc = (tid & 31) * 4;

    float acc[8][8];
#pragma unroll
    for (int i = 0; i < 8; i++)
#pragma unroll
        for (int j = 0; j < 8; j++) acc[i][j] = 0.f;

    if (h < 6) {
        const float* F = (h < 2) ? f_adj : (h < 4) ? f_dist : f_clb;
        const bool soft = (h >= 2);
        float rm = 0.f, ri = 1.f;
        if (soft) {
            const float* RM = (h < 4) ? ws + OFF_RMAXD : ws + OFF_RMAXC;
            const float* RI = (h < 4) ? ws + OFF_RINVD : ws + OFF_RINVC;
            rm = RM[row0 + arow];
            ri = RI[row0 + arow];
        }
        for (int kt = 0; kt < NA; kt += 8) {
            float4 av = *(const float4*)(F + (size_t)(row0 + arow) * NA + kt + ak);
            if (soft) {
                av.x = expf(av.x - rm) * ri; av.y = expf(av.y - rm) * ri;
                av.z = expf(av.z - rm) * ri; av.w = expf(av.w - rm) * ri;
            }
            float4 bv = *(const float4*)(V + (kt + bk) * HIDDEN + h * DH + bc);
            __syncthreads();
            As[ak + 0][arow] = av.x; As[ak + 1][arow] = av.y;
            As[ak + 2][arow] = av.z; As[ak + 3][arow] = av.w;
            *(float4*)&Bs[bk][bc] = bv;
            __syncthreads();
#pragma unroll
            for (int k = 0; k < 8; k++) {
                float4 a0 = *(const float4*)&As[k][ty * 8];
                float4 a1 = *(const float4*)&As[k][ty * 8 + 4];
                float4 b0 = *(const float4*)&Bs[k][tx * 8];
                float4 b1 = *(const float4*)&Bs[k][tx * 8 + 4];
                float a[8] = {a0.x,a0.y,a0.z,a0.w,a1.x,a1.y,a1.z,a1.w};
                float b[8] = {b0.x,b0.y,b0.z,b0.w,b1.x,b1.y,b1.z,b1.w};
#pragma unroll
                for (int i = 0; i < 8; i++)
#pragma unroll
                    for (int j = 0; j < 8; j++)
                        acc[i][j] = fmaf(a[i], b[j], acc[i][j]);
            }
        }
    }
    // + q_h @ M_h  (K = 128)
    for (int kt = 0; kt < DH; kt += 8) {
        float4 av = *(const float4*)(Q + (row0 + arow) * HIDDEN + h * DH + kt + ak);
        float4 bv = *(const float4*)(M + h * DH * DH + (kt + bk) * DH + bc);
        __syncthreads();
        As[ak + 0][arow] = av.x; As[ak + 1][arow] = av.y;
        As[ak + 2][arow] = av.z; As[ak + 3][arow] = av.w;
        *(float4*)&Bs[bk][bc] = bv;
        __syncthreads();
#pragma unroll
        for (int k = 0; k < 8; k++) {
            float4 a0 = *(const float4*)&As[k][ty * 8];
            float4 a1 = *(const float4*)&As[k][ty * 8 + 4];
            float4 b0 = *(const float4*)&Bs[k][tx * 8];
            float4 b1 = *(const float4*)&Bs[k][tx * 8 + 4];
            float a[8] = {a0.x,a0.y,a0.z,a0.w,a1.x,a1.y,a1.z,a1.w};
            float b[8] = {b0.x,b0.y,b0.z,b0.w,b1.x,b1.y,b1.z,b1.w};
#pragma unroll
            for (int i = 0; i < 8; i++)
#pragma unroll
                for (int j = 0; j < 8; j++)
                    acc[i][j] = fmaf(a[i], b[j], acc[i][j]);
        }
    }
#pragma unroll
    for (int i = 0; i < 8; i++) {
        float* dst = RET + (row0 + ty * 8 + i) * HIDDEN + h * DH + tx * 8;
        float o[8];
#pragma unroll
        for (int j = 0; j < 8; j++) o[j] = fmaxf(c_scale * acc[i][j], 0.f);
        *(float4*)dst       = make_float4(o[0], o[1], o[2], o[3]);
        *(float4*)(dst + 4) = make_float4(o[4], o[5], o[6], o[7]);
    }
}

// =====================================================================
// Y = X + RET @ Wo + bo
// =====================================================================
__global__ __launch_bounds__(256) void k_wo(
    float* __restrict__ ws, const float* __restrict__ Wo,
    const float* __restrict__ X, const float* __restrict__ bo)
{
    __shared__ float As[8][132];
    __shared__ float Bs[8][132];
    const float* A = ws + OFF_RET;
    float* Y = ws + OFF_Y;

    const int tid = threadIdx.x;
    const int tx = tid & 15, ty = tid >> 4;
    const int row0 = blockIdx.y * 128, col0 = blockIdx.x * 128;
    const int arow = tid >> 1, ak = (tid & 1) * 4;
    const int bk = tid >> 5, bc = (tid & 31) * 4;

    float acc[8][8];
#pragma unroll
    for (int i = 0; i < 8; i++)
#pragma unroll
        for (int j = 0; j < 8; j++) acc[i][j] = 0.f;

    for (int kt = 0; kt < HIDDEN; kt += 8) {
        float4 av = *(const float4*)(A + (row0 + arow) * HIDDEN + kt + ak);
        float4 bv = *(const float4*)(Wo + (kt + bk) * HIDDEN + col0 + bc);
        __syncthreads();
        As[ak + 0][arow] = av.x; As[ak + 1][arow] = av.y;
        As[ak + 2][arow] = av.z; As[ak + 3][arow] = av.w;
        *(float4*)&Bs[bk][bc] = bv;
        __syncthreads();
#pragma unroll
        for (int k = 0; k < 8; k++) {
            float4 a0 = *(const float4*)&As[k][ty * 8];
            float4 a1 = *(const float4*)&As[k][ty * 8 + 4];
            float4 b0 = *(const float4*)&Bs[k][tx * 8];
            float4 b1 = *(const float4*)&Bs[k][tx * 8 + 4];
            float a[8] = {a0.x,a0.y,a0.z,a0.w,a1.x,a1.y,a1.z,a1.w};
            float b[8] = {b0.x,b0.y,b0.z,b0.w,b1.x,b1.y,b1.z,b1.w};
#pragma unroll
            for (int i = 0; i < 8; i++)
#pragma unroll
                for (int j = 0; j < 8; j++)
                    acc[i][j] = fmaf(a[i], b[j], acc[i][j]);
        }
    }
    float4 bo0 = *(const float4*)(bo + col0 + tx * 8);
    float4 bo1 = *(const float4*)(bo + col0 + tx * 8 + 4);
#pragma unroll
    for (int i = 0; i < 8; i++) {
        const int r = row0 + ty * 8 + i;
        const int c = col0 + tx * 8;
        float4 x0 = *(const float4*)(X + r * HIDDEN + c);
        float4 x1 = *(const float4*)(X + r * HIDDEN + c + 4);
        float* dst = Y + r * HIDDEN + c;
        *(float4*)dst = make_float4(acc[i][0] + x0.x + bo0.x, acc[i][1] + x0.y + bo0.y,
                                    acc[i][2] + x0.z + bo0.z, acc[i][3] + x0.w + bo0.w);
        *(float4*)(dst + 4) = make_float4(acc[i][4] + x1.x + bo1.x, acc[i][5] + x1.y + bo1.y,
                                          acc[i][6] + x1.z + bo1.z, acc[i][7] + x1.w + bo1.w);
    }
}

// =====================================================================
// LayerNorm rows of Y -> mol_vec
// =====================================================================
__global__ __launch_bounds__(256) void k_ln(
    const float* __restrict__ ws, const float* __restrict__ g,
    const float* __restrict__ b, float* __restrict__ out)
{
    const float* Y = ws + OFF_Y;
    const int row = blockIdx.x, t = threadIdx.x;
    float4 v = *(const float4*)(Y + row * HIDDEN + 4 * t);
    float s = v.x + v.y + v.z + v.w;
    for (int off = 32; off; off >>= 1) s += __shfl_xor(s, off);
    __shared__ float sb[4];
    if ((t & 63) == 0) sb[t >> 6] = s;
    __syncthreads();
    const float mu = (sb[0] + sb[1] + sb[2] + sb[3]) * (1.0f / HIDDEN);
    const float dx = v.x - mu, dy = v.y - mu, dz = v.z - mu, dw = v.w - mu;
    float q = dx * dx + dy * dy + dz * dz + dw * dw;
    __syncthreads();
    for (int off = 32; off; off >>= 1) q += __shfl_xor(q, off);
    if ((t & 63) == 0) sb[t >> 6] = q;
    __syncthreads();
    const float var = (sb[0] + sb[1] + sb[2] + sb[3]) * (1.0f / HIDDEN);
    const float rstd = rsqrtf(var + LN_EPS);
    float4 gv = *(const float4*)(g + 4 * t);
    float4 bv = *(const float4*)(b + 4 * t);
    float4 o = make_float4(dx * rstd * gv.x + bv.x, dy * rstd * gv.y + bv.y,
                           dz * rstd * gv.z + bv.z, dw * rstd * gv.w + bv.w);
    *(float4*)(out + row * HIDDEN + 4 * t) = o;
}

// =====================================================================
extern "C" void kernel_launch(void* const* d_in, const int* in_sizes, int n_in,
                              void* d_out, int out_size, void* d_ws, size_t ws_size,
                              hipStream_t stream)
{
    const float* X      = (const float*)d_in[0];
    const float* f_adj  = (const float*)d_in[1];
    const float* f_dist = (const float*)d_in[2];
    const float* f_clb  = (const float*)d_in[3];
    const float* Wq     = (const float*)d_in[4];
    const float* Wk     = (const float*)d_in[5];
    const float* Wv     = (const float*)d_in[6];
    const float* Wo     = (const float*)d_in[7];
    const float* bo     = (const float*)d_in[8];
    const float* ln_g   = (const float*)d_in[9];
    const float* ln_b   = (const float*)d_in[10];

    float* ws = (float*)d_ws;
    float* out = (float*)d_out;
    float* out_scores = out + (size_t)NA * HIDDEN;

    const float c_scale = (float)pow(1.0 - 1.0 / 32.0, 1.0 / sqrt(128.0));

    hipMemsetAsync(ws + OFF_M, 0, NHEADS * DH * DH * sizeof(float), stream);

    k_proj    <<<dim3(8, 32, 3),   256, 0, stream>>>(X, Wq, Wk, Wv, ws);
    k_rowstats<<<dim3(NA, 2),      256, 0, stream>>>(f_dist, f_clb, ws);
    k_ktv     <<<dim3(16, NHEADS), 256, 0, stream>>>(ws);
    k_scores  <<<dim3(32, 32),     256, 0, stream>>>(ws, f_adj, f_dist, f_clb,
                                                     out_scores, c_scale / 8.f, c_scale / 4.f);
    k_ret     <<<dim3(1, 32, NHEADS), 256, 0, stream>>>(ws, f_adj, f_dist, f_clb, c_scale);
    k_wo      <<<dim3(8, 32),      256, 0, stream>>>(ws, Wo, X, bo);
    k_ln      <<<NA,               256, 0, stream>>>(ws, ln_g, ln_b, out);
}

// Round 3
// 613.781 us; speedup vs baseline: 3.2496x; 3.2496x over previous
//
#include <hip/hip_runtime.h>
#include <math.h>

#define NA     4096
#define HID    1024
#define LN_EPS 1e-5f

typedef short s8   __attribute__((ext_vector_type(8)));   // 8 bf16 (4 VGPR) MFMA frag
typedef float f32x4 __attribute__((ext_vector_type(4)));  // MFMA accum

// ---- workspace layout (BYTE offsets), peak ~57 MB ----
#define OFF_XBF   ((size_t)0)              // Xbf [4096][1024] bf16, 8 MB
#define OFF_WQT   ((size_t)8<<20)          // WqT [1024][1024] bf16, 2 MB (transposed)
#define OFF_WKT   ((size_t)10<<20)
#define OFF_WVT   ((size_t)12<<20)
#define OFF_QB    ((size_t)14<<20)         // Q bf16 [4096][1024], 8 MB
#define OFF_KB    ((size_t)22<<20)
#define OFF_VB    ((size_t)30<<20)
#define OFF_RETB  OFF_VB                   // RET bf16 aliases Vb (Vb dead after transKV)
#define OFF_KT    ((size_t)38<<20)         // KT [8*128][4096] bf16, 8 MB
#define OFF_VT    ((size_t)46<<20)
#define OFF_WOT   ((size_t)54<<20)
#define OFF_M2F   ((size_t)56<<20)         // M^T fp32 partial [8][128][128], 512 KB
#define OFF_M2B   (OFF_M2F + ((size_t)512<<10))
#define OFF_RMAXD (OFF_M2F + ((size_t)768<<10))
#define OFF_RINVD (OFF_RMAXD + 16384)
#define OFF_RMAXC (OFF_RINVD + 16384)
#define OFF_RINVC (OFF_RMAXC + 16384)
#define OFF_YF    ((size_t)0)              // Y fp32 [4096][1024] 16MB aliases Xbf+W*T+2MB of Qb (all dead)

__device__ __forceinline__ ushort f2bf(float f) {   // RNE fp32->bf16
    unsigned u = __float_as_uint(f);
    u += 0x7FFFu + ((u >> 16) & 1u);
    return (ushort)(u >> 16);
}

// 16 MFMAs on the staged [128][32] bf16 tiles; wave (wr,wc) owns 64x64.
__device__ __forceinline__ void mfma_step(const short* As, const short* Bs,
                                          f32x4 (&acc)[4][4], int lane, int wr, int wc)
{
    const int r = lane & 15, kg = (lane >> 4) * 8;
    s8 a[4], b[4];
#pragma unroll
    for (int i = 0; i < 4; i++) a[i] = *(const s8*)&As[(wr*64 + i*16 + r)*32 + kg];
#pragma unroll
    for (int j = 0; j < 4; j++) b[j] = *(const s8*)&Bs[(wc*64 + j*16 + r)*32 + kg];
#pragma unroll
    for (int i = 0; i < 4; i++)
#pragma unroll
        for (int j = 0; j < 4; j++)
            acc[i][j] = __builtin_amdgcn_mfma_f32_16x16x32_bf16(a[i], b[j], acc[i][j], 0, 0, 0);
}

// NT GEMM core: C[128][128] tile at (row0,col0) = sum_k A[m][k]*Bt[n][k], bf16 sources.
__device__ __forceinline__ void gemm_bf16_nt(const ushort* A, int lda,
    const ushort* Bt, int ldb, int K, int row0, int col0,
    short* As, short* Bs, f32x4 (&acc)[4][4], int tid)
{
    const int lane = tid & 63, wave = tid >> 6, wr = wave >> 1, wc = wave & 1;
    const int sr = tid >> 1, sc = (tid & 1) * 16;
    const ushort* Ap = A  + (size_t)(row0 + sr) * lda + sc;
    const ushort* Bp = Bt + (size_t)(col0 + sr) * ldb + sc;
    short* Ad = &As[sr * 32 + sc];
    short* Bd = &Bs[sr * 32 + sc];
    for (int kt = 0; kt < K; kt += 32) {
        uint4 a0 = *(const uint4*)(Ap + kt);
        uint4 a1 = *(const uint4*)(Ap + kt + 8);
        uint4 b0 = *(const uint4*)(Bp + kt);
        uint4 b1 = *(const uint4*)(Bp + kt + 8);
        __syncthreads();
        *(uint4*)Ad = a0; *(uint4*)(Ad + 8) = a1;
        *(uint4*)Bd = b0; *(uint4*)(Bd + 8) = b1;
        __syncthreads();
        mfma_step(As, Bs, acc, lane, wr, wc);
    }
}

#define ZERO_ACC(acc) { f32x4 z = {0.f,0.f,0.f,0.f}; \
    _Pragma("unroll") for (int i=0;i<4;i++) _Pragma("unroll") for (int j=0;j<4;j++) acc[i][j]=z; }

// =====================================================================
// prep: z=0 convert X->bf16 ; z=1..4 transpose+convert Wq/Wk/Wv/Wo
// =====================================================================
__global__ __launch_bounds__(256) void k_prep(const float* __restrict__ X,
    const float* __restrict__ Wq, const float* __restrict__ Wk,
    const float* __restrict__ Wv, const float* __restrict__ Wo, char* __restrict__ wsb)
{
    const int z = blockIdx.z, bx = blockIdx.x, by = blockIdx.y, t = threadIdx.x;
    const int lr = t >> 2, jb = t & 3;
    if (z == 0) {
        const float* src = X + (size_t)(by*64 + lr) * HID + bx*64 + jb*16;
        ushort* dst = (ushort*)(wsb + OFF_XBF) + (size_t)(by*64 + lr) * HID + bx*64 + jb*16;
        union { ushort u[16]; uint4 q[2]; } pk;
        union { float f[16]; float4 v[4]; } fa;
#pragma unroll
        for (int m = 0; m < 4; m++) fa.v[m] = ((const float4*)src)[m];
#pragma unroll
        for (int m = 0; m < 16; m++) pk.u[m] = f2bf(fa.f[m]);
        ((uint4*)dst)[0] = pk.q[0]; ((uint4*)dst)[1] = pk.q[1];
        return;
    }
    if (by >= 16) return;
    __shared__ ushort Tl[64][72];
    const float* W = (z == 1) ? Wq : (z == 2) ? Wk : (z == 3) ? Wv : Wo;
    ushort* WT = (ushort*)(wsb + ((z==1)?OFF_WQT:(z==2)?OFF_WKT:(z==3)?OFF_WVT:OFF_WOT));
    const int r0 = by*64, c0 = bx*64;
    const float* src = W + (size_t)(r0 + lr) * HID + c0 + jb*16;
    union { float f[16]; float4 v[4]; } fa;
#pragma unroll
    for (int m = 0; m < 4; m++) fa.v[m] = ((const float4*)src)[m];
#pragma unroll
    for (int m = 0; m < 16; m++) Tl[lr][jb*16 + m] = f2bf(fa.f[m]);
    __syncthreads();
    union { ushort u[16]; uint4 q[2]; } pk;
#pragma unroll
    for (int m = 0; m < 16; m++) pk.u[m] = Tl[jb*16 + m][lr];
    ushort* dst = WT + (size_t)(c0 + lr) * HID + r0 + jb*16;
    ((uint4*)dst)[0] = pk.q[0]; ((uint4*)dst)[1] = pk.q[1];
}

// =====================================================================
// Row softmax stats for f_dist / f_clb
// =====================================================================
__global__ __launch_bounds__(256) void k_rowstats(const float* __restrict__ f_dist,
    const float* __restrict__ f_clb, char* __restrict__ wsb)
{
    const int row = blockIdx.x, mat = blockIdx.y, t = threadIdx.x;
    const float* F = mat ? f_clb : f_dist;
    float* rmax = (float*)(wsb + (mat ? OFF_RMAXC : OFF_RMAXD));
    float* rinv = (float*)(wsb + (mat ? OFF_RINVC : OFF_RINVD));
    float4 v[4];
#pragma unroll
    for (int p = 0; p < 4; p++)
        v[p] = *(const float4*)(F + (size_t)row * NA + 4*t + 1024*p);
    float m = -1e30f;
#pragma unroll
    for (int p = 0; p < 4; p++)
        m = fmaxf(m, fmaxf(fmaxf(v[p].x, v[p].y), fmaxf(v[p].z, v[p].w)));
    for (int off = 32; off; off >>= 1) m = fmaxf(m, __shfl_xor(m, off));
    __shared__ float sb[4];
    if ((t & 63) == 0) sb[t >> 6] = m;
    __syncthreads();
    const float m4 = fmaxf(fmaxf(sb[0], sb[1]), fmaxf(sb[2], sb[3]));
    __syncthreads();
    float s = 0.f;
#pragma unroll
    for (int p = 0; p < 4; p++)
        s += expf(v[p].x-m4) + expf(v[p].y-m4) + expf(v[p].z-m4) + expf(v[p].w-m4);
    for (int off = 32; off; off >>= 1) s += __shfl_xor(s, off);
    if ((t & 63) == 0) sb[t >> 6] = s;
    __syncthreads();
    if (t == 0) { rmax[row] = m4; rinv[row] = 1.0f / (sb[0]+sb[1]+sb[2]+sb[3]); }
}

// =====================================================================
// proj: {Q,K,V}b = Xbf @ W{q,k,v}T^T  (bf16 out)
// =====================================================================
__global__ __launch_bounds__(256) void k_proj(char* __restrict__ wsb)
{
    __shared__ __align__(16) short As[4096], Bs[4096];
    const int z = blockIdx.z;
    const ushort* A  = (const ushort*)(wsb + OFF_XBF);
    const ushort* Bt = (const ushort*)(wsb + ((z==0)?OFF_WQT:(z==1)?OFF_WKT:OFF_WVT));
    ushort* O = (ushort*)(wsb + ((z==0)?OFF_QB:(z==1)?OFF_KB:OFF_VB));
    const int row0 = blockIdx.y*128, col0 = blockIdx.x*128;
    f32x4 acc[4][4]; ZERO_ACC(acc);
    gemm_bf16_nt(A, HID, Bt, HID, HID, row0, col0, As, Bs, acc, threadIdx.x);
    const int lane = threadIdx.x & 63, wave = threadIdx.x >> 6, wr = wave>>1, wc = wave&1;
#pragma unroll
    for (int i = 0; i < 4; i++)
#pragma unroll
    for (int e = 0; e < 4; e++) {
        const int r = row0 + wr*64 + i*16 + (lane>>4)*4 + e;
#pragma unroll
        for (int j = 0; j < 4; j++) {
            const int c = col0 + wc*64 + j*16 + (lane & 15);
            O[(size_t)r*HID + c] = f2bf(acc[i][j][e]);
        }
    }
}

// =====================================================================
// transKV: z=0 Kb->KT, z=1 Vb->VT   (out[h*128+d][n] = in[n][h*128+d])
// =====================================================================
__global__ __launch_bounds__(256) void k_transKV(char* __restrict__ wsb)
{
    const int z = blockIdx.z;
    const ushort* in = (const ushort*)(wsb + (z ? OFF_VB : OFF_KB));
    ushort* out = (ushort*)(wsb + (z ? OFF_VT : OFF_KT));
    const int n0 = blockIdx.y*64, c0 = blockIdx.x*64;
    const int t = threadIdx.x, lr = t >> 2, jb = t & 3;
    __shared__ ushort Tl[64][72];
    const ushort* src = in + (size_t)(n0 + lr) * HID + c0 + jb*16;
    union { ushort u[16]; uint4 q[2]; } pk;
    pk.q[0] = ((const uint4*)src)[0]; pk.q[1] = ((const uint4*)src)[1];
#pragma unroll
    for (int m = 0; m < 16; m++) Tl[lr][jb*16 + m] = pk.u[m];
    __syncthreads();
#pragma unroll
    for (int m = 0; m < 16; m++) pk.u[m] = Tl[jb*16 + m][lr];
    ushort* dst = out + (size_t)(c0 + lr) * NA + n0 + jb*16;
    ((uint4*)dst)[0] = pk.q[0]; ((uint4*)dst)[1] = pk.q[1];
}

// =====================================================================
// ktv: M2[h] = M_h^T = (VT_h)(KT_h)^T, split-K over 16 chunks, atomicAdd fp32
// =====================================================================
__global__ __launch_bounds__(256) void k_ktv(char* __restrict__ wsb)
{
    __shared__ __align__(16) short As[4096], Bs[4096];
    const int ci = blockIdx.x, h = blockIdx.y;
    const ushort* A  = (const ushort*)(wsb + OFF_VT) + (size_t)h*128*NA + ci*256;
    const ushort* Bt = (const ushort*)(wsb + OFF_KT) + (size_t)h*128*NA + ci*256;
    f32x4 acc[4][4]; ZERO_ACC(acc);
    gemm_bf16_nt(A, NA, Bt, NA, 256, 0, 0, As, Bs, acc, threadIdx.x);
    float* M2f = (float*)(wsb + OFF_M2F) + (size_t)h*16384;
    const int lane = threadIdx.x & 63, wave = threadIdx.x >> 6, wr = wave>>1, wc = wave&1;
#pragma unroll
    for (int i = 0; i < 4; i++)
#pragma unroll
    for (int e = 0; e < 4; e++) {
        const int r = wr*64 + i*16 + (lane>>4)*4 + e;
#pragma unroll
        for (int j = 0; j < 4; j++) {
            const int c = wc*64 + j*16 + (lane & 15);
            atomicAdd(&M2f[r*128 + c], acc[i][j][e]);
        }
    }
}

__global__ __launch_bounds__(256) void k_m2cvt(char* __restrict__ wsb)
{
    const int i = (blockIdx.x*256 + threadIdx.x) * 8;
    const float* s = (const float*)(wsb + OFF_M2F);
    ushort* d = (ushort*)(wsb + OFF_M2B);
    union { float f[8]; float4 v[2]; } fa;
    fa.v[0] = *(const float4*)(s + i); fa.v[1] = *(const float4*)(s + i + 4);
    union { ushort u[8]; uint4 q; } pk;
#pragma unroll
    for (int m = 0; m < 8; m++) pk.u[m] = f2bf(fa.f[m]);
    *(uint4*)(d + i) = pk.q;
}

// =====================================================================
// scores: out = c/8 * Qb@Kb^T + c/4 * (adj + softmax(fd) + softmax(fc))  [fp32 bias]
// =====================================================================
__global__ __launch_bounds__(256) void k_scores(char* __restrict__ wsb,
    const float* __restrict__ f_adj, const float* __restrict__ f_dist,
    const float* __restrict__ f_clb, float* __restrict__ outs, float cdiv8, float cdiv4)
{
    __shared__ __align__(16) short As[4096], Bs[4096];
    const int row0 = blockIdx.y*128, col0 = blockIdx.x*128;
    f32x4 acc[4][4]; ZERO_ACC(acc);
    gemm_bf16_nt((const ushort*)(wsb + OFF_QB), HID,
                 (const ushort*)(wsb + OFF_KB), HID, HID, row0, col0, As, Bs, acc, threadIdx.x);
    const float* rmaxd = (const float*)(wsb + OFF_RMAXD);
    const float* rinvd = (const float*)(wsb + OFF_RINVD);
    const float* rmaxc = (const float*)(wsb + OFF_RMAXC);
    const float* rinvc = (const float*)(wsb + OFF_RINVC);
    const int lane = threadIdx.x & 63, wave = threadIdx.x >> 6, wr = wave>>1, wc = wave&1;
#pragma unroll
    for (int i = 0; i < 4; i++)
#pragma unroll
    for (int e = 0; e < 4; e++) {
        const int r = row0 + wr*64 + i*16 + (lane>>4)*4 + e;
        const float rmd = rmaxd[r], rid = rinvd[r], rmc = rmaxc[r], ric = rinvc[r];
#pragma unroll
        for (int j = 0; j < 4; j++) {
            const int c = col0 + wc*64 + j*16 + (lane & 15);
            const size_t idx = (size_t)r * NA + c;
            const float bias = f_adj[idx] + __expf(f_dist[idx]-rmd)*rid
                                          + __expf(f_clb[idx]-rmc)*ric;
            outs[idx] = cdiv8 * acc[i][j][e] + cdiv4 * bias;
        }
    }
}

// =====================================================================
// ret: RETb[:, h*128..] = relu(c*(B_h @ v_h + q_h @ M_h)); B staged on-the-fly
//   z=p: 0->adj(h0,1) 1->softmax(fd)(h2,3) 2->softmax(fc)(h4,5) 3->none(h6,7)
// =====================================================================
__global__ __launch_bounds__(256) void k_ret(char* __restrict__ wsb,
    const float* __restrict__ f_adj, const float* __restrict__ f_dist,
    const float* __restrict__ f_clb, float c_scale)
{
    __shared__ __align__(16) short As[4096], Bs[4096];
    const int p = blockIdx.z, x = blockIdx.x, row0 = blockIdx.y*128;
    const int tid = threadIdx.x, lane = tid & 63, wave = tid >> 6, wr = wave>>1, wc = wave&1;
    const int sr = tid >> 1, sc = (tid & 1) * 16;
    const int h = (p < 3) ? p*2 + x : 6 + x;
    f32x4 acc[4][4]; ZERO_ACC(acc);
    short* Ad = &As[sr*32 + sc];
    short* Bd = &Bs[sr*32 + sc];

    if (p < 3) {
        const float* F = (p == 0) ? f_adj : (p == 1) ? f_dist : f_clb;
        const bool sm = (p > 0);
        float rm = 0.f, ri = 1.f;
        if (sm) {
            const float* RM = (const float*)(wsb + ((p==1) ? OFF_RMAXD : OFF_RMAXC));
            const float* RI = (const float*)(wsb + ((p==1) ? OFF_RINVD : OFF_RINVC));
            rm = RM[row0 + sr]; ri = RI[row0 + sr];
        }
        const float* Fp = F + (size_t)(row0 + sr) * NA + sc;
        const ushort* Bp = (const ushort*)(wsb + OFF_VT) + (size_t)(p*256 + x*128 + sr) * NA + sc;
        for (int kt = 0; kt < NA; kt += 32) {
            union { float f[16]; float4 v[4]; } fa;
#pragma unroll
            for (int m = 0; m < 4; m++) fa.v[m] = *(const float4*)(Fp + kt + m*4);
            uint4 b0 = *(const uint4*)(Bp + kt);
            uint4 b1 = *(const uint4*)(Bp + kt + 8);
            if (sm) {
#pragma unroll
                for (int m = 0; m < 16; m++) fa.f[m] = __expf(fa.f[m] - rm) * ri;
            }
            union { ushort u[16]; uint4 q[2]; } pk;
#pragma unroll
            for (int m = 0; m < 16; m++) pk.u[m] = f2bf(fa.f[m]);
            __syncthreads();
            *(uint4*)Ad = pk.q[0]; *(uint4*)(Ad + 8) = pk.q[1];
            *(uint4*)Bd = b0;      *(uint4*)(Bd + 8) = b1;
            __syncthreads();
            mfma_step(As, Bs, acc, lane, wr, wc);
        }
    }
    // + q_h @ M_h  (Bt = M2b[h] = M_h^T, K=128)
    const ushort* Ap2 = (const ushort*)(wsb + OFF_QB) + (size_t)(row0 + sr) * HID + h*128 + sc;
    const ushort* Bp2 = (const ushort*)(wsb + OFF_M2B) + (size_t)h*16384 + sr*128 + sc;
    for (int kt = 0; kt < 128; kt += 32) {
        uint4 a0 = *(const uint4*)(Ap2 + kt), a1 = *(const uint4*)(Ap2 + kt + 8);
        uint4 b0 = *(const uint4*)(Bp2 + kt), b1 = *(const uint4*)(Bp2 + kt + 8);
        __syncthreads();
        *(uint4*)Ad = a0; *(uint4*)(Ad + 8) = a1;
        *(uint4*)Bd = b0; *(uint4*)(Bd + 8) = b1;
        __syncthreads();
        mfma_step(As, Bs, acc, lane, wr, wc);
    }
    ushort* R = (ushort*)(wsb + OFF_RETB);
#pragma unroll
    for (int i = 0; i < 4; i++)
#pragma unroll
    for (int e = 0; e < 4; e++) {
        const int r = row0 + wr*64 + i*16 + (lane>>4)*4 + e;
#pragma unroll
        for (int j = 0; j < 4; j++) {
            const int c = wc*64 + j*16 + (lane & 15);
            R[(size_t)r*HID + h*128 + c] = f2bf(fmaxf(c_scale * acc[i][j][e], 0.f));
        }
    }
}

// =====================================================================
// wo: Yf = X + RETb @ WoT^T + bo   (fp32 out)
// =====================================================================
__global__ __launch_bounds__(256) void k_wo(char* __restrict__ wsb,
    const float* __restrict__ X, const float* __restrict__ bo)
{
    __shared__ __align__(16) short As[4096], Bs[4096];
    const int row0 = blockIdx.y*128, col0 = blockIdx.x*128;
    f32x4 acc[4][4]; ZERO_ACC(acc);
    gemm_bf16_nt((const ushort*)(wsb + OFF_RETB), HID,
                 (const ushort*)(wsb + OFF_WOT), HID, HID, row0, col0, As, Bs, acc, threadIdx.x);
    float* Y = (float*)(wsb + OFF_YF);
    const int lane = threadIdx.x & 63, wave = threadIdx.x >> 6, wr = wave>>1, wc = wave&1;
#pragma unroll
    for (int i = 0; i < 4; i++)
#pragma unroll
    for (int e = 0; e < 4; e++) {
        const int r = row0 + wr*64 + i*16 + (lane>>4)*4 + e;
#pragma unroll
        for (int j = 0; j < 4; j++) {
            const int c = col0 + wc*64 + j*16 + (lane & 15);
            Y[(size_t)r*HID + c] = acc[i][j][e] + X[(size_t)r*HID + c] + bo[c];
        }
    }
}

// =====================================================================
// LayerNorm rows of Yf -> mol_vec
// =====================================================================
__global__ __launch_bounds__(256) void k_ln(const char* __restrict__ wsb,
    const float* __restrict__ g, const float* __restrict__ b, float* __restrict__ out)
{
    const float* Y = (const float*)(wsb + OFF_YF);
    const int row = blockIdx.x, t = threadIdx.x;
    float4 v = *(const float4*)(Y + (size_t)row * HID + 4*t);
    float s = v.x + v.y + v.z + v.w;
    for (int off = 32; off; off >>= 1) s += __shfl_xor(s, off);
    __shared__ float sb[4];
    if ((t & 63) == 0) sb[t >> 6] = s;
    __syncthreads();
    const float mu = (sb[0]+sb[1]+sb[2]+sb[3]) * (1.0f / HID);
    const float dx = v.x-mu, dy = v.y-mu, dz = v.z-mu, dw = v.w-mu;
    float q = dx*dx + dy*dy + dz*dz + dw*dw;
    __syncthreads();
    for (int off = 32; off; off >>= 1) q += __shfl_xor(q, off);
    if ((t & 63) == 0) sb[t >> 6] = q;
    __syncthreads();
    const float var = (sb[0]+sb[1]+sb[2]+sb[3]) * (1.0f / HID);
    const float rstd = rsqrtf(var + LN_EPS);
    float4 gv = *(const float4*)(g + 4*t);
    float4 bv = *(const float4*)(b + 4*t);
    float4 o = make_float4(dx*rstd*gv.x + bv.x, dy*rstd*gv.y + bv.y,
                           dz*rstd*gv.z + bv.z, dw*rstd*gv.w + bv.w);
    *(float4*)(out + (size_t)row * HID + 4*t) = o;
}

// =====================================================================
extern "C" void kernel_launch(void* const* d_in, const int* in_sizes, int n_in,
                              void* d_out, int out_size, void* d_ws, size_t ws_size,
                              hipStream_t stream)
{
    const float* X      = (const float*)d_in[0];
    const float* f_adj  = (const float*)d_in[1];
    const float* f_dist = (const float*)d_in[2];
    const float* f_clb  = (const float*)d_in[3];
    const float* Wq     = (const float*)d_in[4];
    const float* Wk     = (const float*)d_in[5];
    const float* Wv     = (const float*)d_in[6];
    const float* Wo     = (const float*)d_in[7];
    const float* bo     = (const float*)d_in[8];
    const float* ln_g   = (const float*)d_in[9];
    const float* ln_b   = (const float*)d_in[10];

    char* wsb = (char*)d_ws;
    float* out = (float*)d_out;
    float* out_scores = out + (size_t)NA * HID;

    const float c_scale = (float)pow(1.0 - 1.0/32.0, 1.0 / sqrt(128.0));

    hipMemsetAsync(wsb + OFF_M2F, 0, (size_t)512 << 10, stream);

    k_prep    <<<dim3(16, 64, 5), 256, 0, stream>>>(X, Wq, Wk, Wv, Wo, wsb);
    k_rowstats<<<dim3(NA, 2),     256, 0, stream>>>(f_dist, f_clb, wsb);
    k_proj    <<<dim3(8, 32, 3),  256, 0, stream>>>(wsb);
    k_transKV <<<dim3(16, 64, 2), 256, 0, stream>>>(wsb);
    k_ktv     <<<dim3(16, 8),     256, 0, stream>>>(wsb);
    k_m2cvt   <<<64,              256, 0, stream>>>(wsb);
    k_scores  <<<dim3(32, 32),    256, 0, stream>>>(wsb, f_adj, f_dist, f_clb,
                                                    out_scores, c_scale/8.f, c_scale/4.f);
    k_ret     <<<dim3(2, 32, 4),  256, 0, stream>>>(wsb, f_adj, f_dist, f_clb, c_scale);
    k_wo      <<<dim3(8, 32),     256, 0, stream>>>(wsb, X, bo);
    k_ln      <<<NA,              256, 0, stream>>>(wsb, ln_g, ln_b, out);
}

// Round 5
// 551.597 us; speedup vs baseline: 3.6160x; 1.1127x over previous
//
#include <hip/hip_runtime.h>
#include <math.h>

#define NA     4096
#define HID    1024
#define LN_EPS 1e-5f
#define LDSW   40   // padded LDS row stride (shorts): 32 data + 8 pad -> <=2-way bank conflicts

typedef short s8   __attribute__((ext_vector_type(8)));
typedef float f32x4 __attribute__((ext_vector_type(4)));

// ---- workspace layout (BYTE offsets), peak ~57 MB ----
#define OFF_XBF   ((size_t)0)              // [4096][1024] bf16, 8 MB (dead after k_proj)
#define OFF_WQT   ((size_t)8<<20)          // 2 MB each (dead after k_proj)
#define OFF_WKT   ((size_t)10<<20)
#define OFF_WVT   ((size_t)12<<20)
#define OFF_QB    ((size_t)14<<20)         // 8 MB (dead after k_retfin)
#define OFF_KB    ((size_t)22<<20)         // 8 MB (dead after k_scores)
#define OFF_VB    ((size_t)30<<20)         // 8 MB (dead after k_transKV)
#define OFF_KT    ((size_t)38<<20)         // 8 MB (dead after k_ktv)
#define OFF_VT    ((size_t)46<<20)         // 8 MB (dead after k_ret2)
#define OFF_WOT   ((size_t)54<<20)         // 2 MB (dead after k_wo)
#define OFF_M2F   ((size_t)56<<20)         // fp32 [8][128][128], 512 KB
#define OFF_M2B   (OFF_M2F + ((size_t)512<<10))
#define OFF_RMAXD (OFF_M2F + ((size_t)768<<10))
#define OFF_RINVD (OFF_RMAXD + 16384)
#define OFF_RMAXC (OFF_RINVD + 16384)
#define OFF_RINVC (OFF_RMAXC + 16384)
#define OFF_RETF  ((size_t)22<<20)         // fp32 [4096][768], 12 MB; aliases KB + VB[0:4M]
#define OFF_RETB  ((size_t)34<<20)         // bf16 [4096][1024], 8 MB; aliases VB[4:8M] + KT[0:4M]
#define OFF_YF    ((size_t)0)              // fp32 [4096][1024], 16 MB; aliases XBF..QB[0:2M]

__device__ __forceinline__ ushort f2bf(float f) {   // RNE fp32->bf16
    unsigned u = __float_as_uint(f);
    u += 0x7FFFu + ((u >> 16) & 1u);
    return (ushort)(u >> 16);
}

// 16 MFMAs on staged tiles (row stride LDSW). Wave (wr,wc) owns 64x64.
__device__ __forceinline__ void mfma_tile(const short* As, const short* Bs,
                                          f32x4 (&acc)[4][4], int lane, int wr, int wc)
{
    const int r = lane & 15, kg = (lane >> 4) * 8;
    s8 a[4], b[4];
#pragma unroll
    for (int i = 0; i < 4; i++) a[i] = *(const s8*)&As[(wr*64 + i*16 + r)*LDSW + kg];
#pragma unroll
    for (int j = 0; j < 4; j++) b[j] = *(const s8*)&Bs[(wc*64 + j*16 + r)*LDSW + kg];
#pragma unroll
    for (int i = 0; i < 4; i++)
#pragma unroll
        for (int j = 0; j < 4; j++)
            acc[i][j] = __builtin_amdgcn_mfma_f32_16x16x32_bf16(a[i], b[j], acc[i][j], 0, 0, 0);
}

// NT GEMM core (256 thr, 4 waves 2x2): C128x128 at (row0,col0) = sum_k A[m][k]*Bt[n][k]
__device__ __forceinline__ void gemm_bf16_nt(const ushort* A, int lda,
    const ushort* Bt, int ldb, int K, int row0, int col0,
    short* As, short* Bs, f32x4 (&acc)[4][4], int tid)
{
    const int lane = tid & 63, wave = tid >> 6, wr = wave >> 1, wc = wave & 1;
    const int sr = tid >> 1, sc = (tid & 1) * 16;
    const ushort* Ap = A  + (size_t)(row0 + sr) * lda + sc;
    const ushort* Bp = Bt + (size_t)(col0 + sr) * ldb + sc;
    short* Ad = &As[sr * LDSW + sc];
    short* Bd = &Bs[sr * LDSW + sc];
    for (int kt = 0; kt < K; kt += 32) {
        uint4 a0 = *(const uint4*)(Ap + kt);
        uint4 a1 = *(const uint4*)(Ap + kt + 8);
        uint4 b0 = *(const uint4*)(Bp + kt);
        uint4 b1 = *(const uint4*)(Bp + kt + 8);
        __syncthreads();
        *(uint4*)Ad = a0; *(uint4*)(Ad + 8) = a1;
        *(uint4*)Bd = b0; *(uint4*)(Bd + 8) = b1;
        __syncthreads();
        mfma_tile(As, Bs, acc, lane, wr, wc);
    }
}

#define ZERO_ACC(acc) { f32x4 z = {0.f,0.f,0.f,0.f}; \
    _Pragma("unroll") for (int i=0;i<4;i++) _Pragma("unroll") for (int j=0;j<4;j++) acc[i][j]=z; }

// =====================================================================
// prep: z=0 X->bf16 ; z=1..4 transpose+convert Wq/Wk/Wv/Wo
// =====================================================================
__global__ __launch_bounds__(256) void k_prep(const float* __restrict__ X,
    const float* __restrict__ Wq, const float* __restrict__ Wk,
    const float* __restrict__ Wv, const float* __restrict__ Wo, char* __restrict__ wsb)
{
    const int z = blockIdx.z, bx = blockIdx.x, by = blockIdx.y, t = threadIdx.x;
    const int lr = t >> 2, jb = t & 3;
    if (z == 0) {
        const float* src = X + (size_t)(by*64 + lr) * HID + bx*64 + jb*16;
        ushort* dst = (ushort*)(wsb + OFF_XBF) + (size_t)(by*64 + lr) * HID + bx*64 + jb*16;
        union { ushort u[16]; uint4 q[2]; } pk;
        union { float f[16]; float4 v[4]; } fa;
#pragma unroll
        for (int m = 0; m < 4; m++) fa.v[m] = ((const float4*)src)[m];
#pragma unroll
        for (int m = 0; m < 16; m++) pk.u[m] = f2bf(fa.f[m]);
        ((uint4*)dst)[0] = pk.q[0]; ((uint4*)dst)[1] = pk.q[1];
        return;
    }
    if (by >= 16) return;
    __shared__ ushort Tl[64][72];
    const float* W = (z == 1) ? Wq : (z == 2) ? Wk : (z == 3) ? Wv : Wo;
    ushort* WT = (ushort*)(wsb + ((z==1)?OFF_WQT:(z==2)?OFF_WKT:(z==3)?OFF_WVT:OFF_WOT));
    const int r0 = by*64, c0 = bx*64;
    const float* src = W + (size_t)(r0 + lr) * HID + c0 + jb*16;
    union { float f[16]; float4 v[4]; } fa;
#pragma unroll
    for (int m = 0; m < 4; m++) fa.v[m] = ((const float4*)src)[m];
#pragma unroll
    for (int m = 0; m < 16; m++) Tl[lr][jb*16 + m] = f2bf(fa.f[m]);
    __syncthreads();
    union { ushort u[16]; uint4 q[2]; } pk;
#pragma unroll
    for (int m = 0; m < 16; m++) pk.u[m] = Tl[jb*16 + m][lr];
    ushort* dst = WT + (size_t)(c0 + lr) * HID + r0 + jb*16;
    ((uint4*)dst)[0] = pk.q[0]; ((uint4*)dst)[1] = pk.q[1];
}

// =====================================================================
// Row softmax stats for f_dist / f_clb
// =====================================================================
__global__ __launch_bounds__(256) void k_rowstats(const float* __restrict__ f_dist,
    const float* __restrict__ f_clb, char* __restrict__ wsb)
{
    const int row = blockIdx.x, mat = blockIdx.y, t = threadIdx.x;
    const float* F = mat ? f_clb : f_dist;
    float* rmax = (float*)(wsb + (mat ? OFF_RMAXC : OFF_RMAXD));
    float* rinv = (float*)(wsb + (mat ? OFF_RINVC : OFF_RINVD));
    float4 v[4];
#pragma unroll
    for (int p = 0; p < 4; p++)
        v[p] = *(const float4*)(F + (size_t)row * NA + 4*t + 1024*p);
    float m = -1e30f;
#pragma unroll
    for (int p = 0; p < 4; p++)
        m = fmaxf(m, fmaxf(fmaxf(v[p].x, v[p].y), fmaxf(v[p].z, v[p].w)));
    for (int off = 32; off; off >>= 1) m = fmaxf(m, __shfl_xor(m, off));
    __shared__ float sb[4];
    if ((t & 63) == 0) sb[t >> 6] = m;
    __syncthreads();
    const float m4 = fmaxf(fmaxf(sb[0], sb[1]), fmaxf(sb[2], sb[3]));
    __syncthreads();
    float s = 0.f;
#pragma unroll
    for (int p = 0; p < 4; p++)
        s += expf(v[p].x-m4) + expf(v[p].y-m4) + expf(v[p].z-m4) + expf(v[p].w-m4);
    for (int off = 32; off; off >>= 1) s += __shfl_xor(s, off);
    if ((t & 63) == 0) sb[t >> 6] = s;
    __syncthreads();
    if (t == 0) { rmax[row] = m4; rinv[row] = 1.0f / (sb[0]+sb[1]+sb[2]+sb[3]); }
}

// =====================================================================
// proj: {Q,K,V}b = Xbf @ W{q,k,v}T^T
// =====================================================================
__global__ __launch_bounds__(256) void k_proj(char* __restrict__ wsb)
{
    __shared__ __align__(16) short As[128*LDSW], Bs[128*LDSW];
    const int z = blockIdx.z;
    const ushort* A  = (const ushort*)(wsb + OFF_XBF);
    const ushort* Bt = (const ushort*)(wsb + ((z==0)?OFF_WQT:(z==1)?OFF_WKT:OFF_WVT));
    ushort* O = (ushort*)(wsb + ((z==0)?OFF_QB:(z==1)?OFF_KB:OFF_VB));
    const int row0 = blockIdx.y*128, col0 = blockIdx.x*128;
    f32x4 acc[4][4]; ZERO_ACC(acc);
    gemm_bf16_nt(A, HID, Bt, HID, HID, row0, col0, As, Bs, acc, threadIdx.x);
    const int lane = threadIdx.x & 63, wave = threadIdx.x >> 6, wr = wave>>1, wc = wave&1;
#pragma unroll
    for (int i = 0; i < 4; i++)
#pragma unroll
    for (int e = 0; e < 4; e++) {
        const int r = row0 + wr*64 + i*16 + (lane>>4)*4 + e;
#pragma unroll
        for (int j = 0; j < 4; j++) {
            const int c = col0 + wc*64 + j*16 + (lane & 15);
            O[(size_t)r*HID + c] = f2bf(acc[i][j][e]);
        }
    }
}

// =====================================================================
// transKV: z=0 Kb->KT, z=1 Vb->VT
// =====================================================================
__global__ __launch_bounds__(256) void k_transKV(char* __restrict__ wsb)
{
    const int z = blockIdx.z;
    const ushort* in = (const ushort*)(wsb + (z ? OFF_VB : OFF_KB));
    ushort* out = (ushort*)(wsb + (z ? OFF_VT : OFF_KT));
    const int n0 = blockIdx.y*64, c0 = blockIdx.x*64;
    const int t = threadIdx.x, lr = t >> 2, jb = t & 3;
    __shared__ ushort Tl[64][72];
    const ushort* src = in + (size_t)(n0 + lr) * HID + c0 + jb*16;
    union { ushort u[16]; uint4 q[2]; } pk;
    pk.q[0] = ((const uint4*)src)[0]; pk.q[1] = ((const uint4*)src)[1];
#pragma unroll
    for (int m = 0; m < 16; m++) Tl[lr][jb*16 + m] = pk.u[m];
    __syncthreads();
#pragma unroll
    for (int m = 0; m < 16; m++) pk.u[m] = Tl[jb*16 + m][lr];
    ushort* dst = out + (size_t)(c0 + lr) * NA + n0 + jb*16;
    ((uint4*)dst)[0] = pk.q[0]; ((uint4*)dst)[1] = pk.q[1];
}

// =====================================================================
// ktv: M2[h] = M_h^T = (VT_h)(KT_h)^T, split over 16 n-chunks, atomicAdd fp32
// =====================================================================
__global__ __launch_bounds__(256) void k_ktv(char* __restrict__ wsb)
{
    __shared__ __align__(16) short As[128*LDSW], Bs[128*LDSW];
    const int ci = blockIdx.x, h = blockIdx.y;
    const ushort* A  = (const ushort*)(wsb + OFF_VT) + (size_t)h*128*NA + ci*256;
    const ushort* Bt = (const ushort*)(wsb + OFF_KT) + (size_t)h*128*NA + ci*256;
    f32x4 acc[4][4]; ZERO_ACC(acc);
    gemm_bf16_nt(A, NA, Bt, NA, 256, 0, 0, As, Bs, acc, threadIdx.x);
    float* M2f = (float*)(wsb + OFF_M2F) + (size_t)h*16384;
    const int lane = threadIdx.x & 63, wave = threadIdx.x >> 6, wr = wave>>1, wc = wave&1;
#pragma unroll
    for (int i = 0; i < 4; i++)
#pragma unroll
    for (int e = 0; e < 4; e++) {
        const int r = wr*64 + i*16 + (lane>>4)*4 + e;
#pragma unroll
        for (int j = 0; j < 4; j++) {
            const int c = wc*64 + j*16 + (lane & 15);
            atomicAdd(&M2f[r*128 + c], acc[i][j][e]);
        }
    }
}

__global__ __launch_bounds__(256) void k_m2cvt(char* __restrict__ wsb)
{
    const int i = (blockIdx.x*256 + threadIdx.x) * 8;
    const float* s = (const float*)(wsb + OFF_M2F);
    ushort* d = (ushort*)(wsb + OFF_M2B);
    union { float f[8]; float4 v[2]; } fa;
    fa.v[0] = *(const float4*)(s + i); fa.v[1] = *(const float4*)(s + i + 4);
    union { ushort u[8]; uint4 q; } pk;
#pragma unroll
    for (int m = 0; m < 8; m++) pk.u[m] = f2bf(fa.f[m]);
    *(uint4*)(d + i) = pk.q;
}

// =====================================================================
// scores: out = c/8 * Qb@Kb^T + c/4 * (adj + softmax(fd) + softmax(fc))
// =====================================================================
__global__ __launch_bounds__(256) void k_scores(char* __restrict__ wsb,
    const float* __restrict__ f_adj, const float* __restrict__ f_dist,
    const float* __restrict__ f_clb, float* __restrict__ outs, float cdiv8, float cdiv4)
{
    __shared__ __align__(16) short As[128*LDSW], Bs[128*LDSW];
    const int row0 = blockIdx.y*128, col0 = blockIdx.x*128;
    f32x4 acc[4][4]; ZERO_ACC(acc);
    gemm_bf16_nt((const ushort*)(wsb + OFF_QB), HID,
                 (const ushort*)(wsb + OFF_KB), HID, HID, row0, col0, As, Bs, acc, threadIdx.x);
    const float* rmaxd = (const float*)(wsb + OFF_RMAXD);
    const float* rinvd = (const float*)(wsb + OFF_RINVD);
    const float* rmaxc = (const float*)(wsb + OFF_RMAXC);
    const float* rinvc = (const float*)(wsb + OFF_RINVC);
    const int lane = threadIdx.x & 63, wave = threadIdx.x >> 6, wr = wave>>1, wc = wave&1;
#pragma unroll
    for (int i = 0; i < 4; i++)
#pragma unroll
    for (int e = 0; e < 4; e++) {
        const int r = row0 + wr*64 + i*16 + (lane>>4)*4 + e;
        const float rmd = rmaxd[r], rid = rinvd[r], rmc = rmaxc[r], ric = rinvc[r];
#pragma unroll
        for (int j = 0; j < 4; j++) {
            const int c = col0 + wc*64 + j*16 + (lane & 15);
            const size_t idx = (size_t)r * NA + c;
            const float bias = f_adj[idx] + __expf(f_dist[idx]-rmd)*rid
                                          + __expf(f_clb[idx]-rmc)*ric;
            outs[idx] = cdiv8 * acc[i][j][e] + cdiv4 * bias;
        }
    }
}

// =====================================================================
// ret2: RETF[:, p*256..+256) += B_p @ [v_2p | v_2p+1]  (merged head pair,
//       split-K x4, fp32 atomic accum). A staged on the fly from fp32 F.
// =====================================================================
__global__ __launch_bounds__(512, 2) void k_ret2(char* __restrict__ wsb,
    const float* __restrict__ f_adj, const float* __restrict__ f_dist,
    const float* __restrict__ f_clb)
{
    __shared__ __align__(16) short As[128*LDSW];
    __shared__ __align__(16) short Bs[256*LDSW];
    const int kc = blockIdx.x;            // K chunk 0..3 (1024 each)
    const int row0 = blockIdx.y * 128;
    const int p = blockIdx.z;             // pair 0..2
    const int tid = threadIdx.x, lane = tid & 63, wave = tid >> 6;
    const int wr = wave >> 2, wc = wave & 3;      // 2 x 4 waves over 128x256
    const int ar = tid >> 2, ac = (tid & 3) * 8;  // A stage: 128 rows x 32
    const int br = tid >> 1, bc = (tid & 1) * 16; // B stage: 256 rows x 32

    const float* F = (p == 0) ? f_adj : (p == 1) ? f_dist : f_clb;
    float rm = 0.f, ri = 1.f;
    if (p) {
        rm = ((const float*)(wsb + ((p==1) ? OFF_RMAXD : OFF_RMAXC)))[row0 + ar];
        ri = ((const float*)(wsb + ((p==1) ? OFF_RINVD : OFF_RINVC)))[row0 + ar];
    }
    const float*  Fp = F + (size_t)(row0 + ar) * NA + kc*1024 + ac;
    const ushort* Bp = (const ushort*)(wsb + OFF_VT) + (size_t)(p*256 + br) * NA + kc*1024 + bc;
    short* Ad = &As[ar * LDSW + ac];
    short* Bd = &Bs[br * LDSW + bc];

    f32x4 acc[4][4]; ZERO_ACC(acc);
    for (int kt = 0; kt < 1024; kt += 32) {
        union { float f[8]; float4 v[2]; } fa;
        fa.v[0] = *(const float4*)(Fp + kt);
        fa.v[1] = *(const float4*)(Fp + kt + 4);
        uint4 b0 = *(const uint4*)(Bp + kt);
        uint4 b1 = *(const uint4*)(Bp + kt + 8);
        if (p) {
#pragma unroll
            for (int m = 0; m < 8; m++) fa.f[m] = __expf(fa.f[m] - rm) * ri;
        }
        union { ushort u[8]; uint4 q; } pk;
#pragma unroll
        for (int m = 0; m < 8; m++) pk.u[m] = f2bf(fa.f[m]);
        __syncthreads();
        *(uint4*)Ad = pk.q;
        *(uint4*)Bd = b0; *(uint4*)(Bd + 8) = b1;
        __syncthreads();
        mfma_tile(As, Bs, acc, lane, wr, wc);
    }
    float* RF = (float*)(wsb + OFF_RETF);
#pragma unroll
    for (int i = 0; i < 4; i++)
#pragma unroll
    for (int e = 0; e < 4; e++) {
        const int r = row0 + wr*64 + i*16 + (lane>>4)*4 + e;
#pragma unroll
        for (int j = 0; j < 4; j++) {
            const int c = p*256 + wc*64 + j*16 + (lane & 15);
            atomicAdd(&RF[(size_t)r * 768 + c], acc[i][j][e]);
        }
    }
}

// =====================================================================
// retfin: RETB = relu(c * (q_h @ M_h + RETF[bias part])), bf16 out
// =====================================================================
__global__ __launch_bounds__(256) void k_retfin(char* __restrict__ wsb, float c_scale)
{
    __shared__ __align__(16) short As[128*LDSW], Bs[128*LDSW];
    const int h = blockIdx.x, row0 = blockIdx.y * 128;
    const ushort* A  = (const ushort*)(wsb + OFF_QB) + (size_t)row0 * HID + h*128;
    const ushort* Bt = (const ushort*)(wsb + OFF_M2B) + (size_t)h * 16384;
    f32x4 acc[4][4]; ZERO_ACC(acc);
    gemm_bf16_nt(A, HID, Bt, 128, 128, 0, 0, As, Bs, acc, threadIdx.x);
    const float* RF = (const float*)(wsb + OFF_RETF);
    ushort* RB = (ushort*)(wsb + OFF_RETB);
    const int lane = threadIdx.x & 63, wave = threadIdx.x >> 6, wr = wave>>1, wc = wave&1;
#pragma unroll
    for (int i = 0; i < 4; i++)
#pragma unroll
    for (int e = 0; e < 4; e++) {
        const int r = row0 + wr*64 + i*16 + (lane>>4)*4 + e;
#pragma unroll
        for (int j = 0; j < 4; j++) {
            const int cl = wc*64 + j*16 + (lane & 15);
            const int col = h*128 + cl;
            float v = acc[i][j][e];
            if (h < 6) v += RF[(size_t)r * 768 + col];
            RB[(size_t)r * HID + col] = f2bf(fmaxf(c_scale * v, 0.f));
        }
    }
}

// =====================================================================
// wo: Yf = X + RETB @ WoT^T + bo
// =====================================================================
__global__ __launch_bounds__(256) void k_wo(char* __restrict__ wsb,
    const float* __restrict__ X, const float* __restrict__ bo)
{
    __shared__ __align__(16) short As[128*LDSW], Bs[128*LDSW];
    const int row0 = blockIdx.y*128, col0 = blockIdx.x*128;
    f32x4 acc[4][4]; ZERO_ACC(acc);
    gemm_bf16_nt((const ushort*)(wsb + OFF_RETB), HID,
                 (const ushort*)(wsb + OFF_WOT), HID, HID, row0, col0, As, Bs, acc, threadIdx.x);
    float* Y = (float*)(wsb + OFF_YF);
    const int lane = threadIdx.x & 63, wave = threadIdx.x >> 6, wr = wave>>1, wc = wave&1;
#pragma unroll
    for (int i = 0; i < 4; i++)
#pragma unroll
    for (int e = 0; e < 4; e++) {
        const int r = row0 + wr*64 + i*16 + (lane>>4)*4 + e;
#pragma unroll
        for (int j = 0; j < 4; j++) {
            const int c = col0 + wc*64 + j*16 + (lane & 15);
            Y[(size_t)r*HID + c] = acc[i][j][e] + X[(size_t)r*HID + c] + bo[c];
        }
    }
}

// =====================================================================
// LayerNorm rows of Yf -> mol_vec
// =====================================================================
__global__ __launch_bounds__(256) void k_ln(const char* __restrict__ wsb,
    const float* __restrict__ g, const float* __restrict__ b, float* __restrict__ out)
{
    const float* Y = (const float*)(wsb + OFF_YF);
    const int row = blockIdx.x, t = threadIdx.x;
    float4 v = *(const float4*)(Y + (size_t)row * HID + 4*t);
    float s = v.x + v.y + v.z + v.w;
    for (int off = 32; off; off >>= 1) s += __shfl_xor(s, off);
    __shared__ float sb[4];
    if ((t & 63) == 0) sb[t >> 6] = s;
    __syncthreads();
    const float mu = (sb[0]+sb[1]+sb[2]+sb[3]) * (1.0f / HID);
    const float dx = v.x-mu, dy = v.y-mu, dz = v.z-mu, dw = v.w-mu;
    float q = dx*dx + dy*dy + dz*dz + dw*dw;
    __syncthreads();
    for (int off = 32; off; off >>= 1) q += __shfl_xor(q, off);
    if ((t & 63) == 0) sb[t >> 6] = q;
    __syncthreads();
    const float var = (sb[0]+sb[1]+sb[2]+sb[3]) * (1.0f / HID);
    const float rstd = rsqrtf(var + LN_EPS);
    float4 gv = *(const float4*)(g + 4*t);
    float4 bv = *(const float4*)(b + 4*t);
    float4 o = make_float4(dx*rstd*gv.x + bv.x, dy*rstd*gv.y + bv.y,
                           dz*rstd*gv.z + bv.z, dw*rstd*gv.w + bv.w);
    *(float4*)(out + (size_t)row * HID + 4*t) = o;
}

// =====================================================================
extern "C" void kernel_launch(void* const* d_in, const int* in_sizes, int n_in,
                              void* d_out, int out_size, void* d_ws, size_t ws_size,
                              hipStream_t stream)
{
    const float* X      = (const float*)d_in[0];
    const float* f_adj  = (const float*)d_in[1];
    const float* f_dist = (const float*)d_in[2];
    const float* f_clb  = (const float*)d_in[3];
    const float* Wq     = (const float*)d_in[4];
    const float* Wk     = (const float*)d_in[5];
    const float* Wv     = (const float*)d_in[6];
    const float* Wo     = (const float*)d_in[7];
    const float* bo     = (const float*)d_in[8];
    const float* ln_g   = (const float*)d_in[9];
    const float* ln_b   = (const float*)d_in[10];

    char* wsb = (char*)d_ws;
    float* out = (float*)d_out;
    float* out_scores = out + (size_t)NA * HID;

    const float c_scale = (float)pow(1.0 - 1.0/32.0, 1.0 / sqrt(128.0));

    hipMemsetAsync(wsb + OFF_M2F, 0, (size_t)512 << 10, stream);

    k_prep    <<<dim3(16, 64, 5), 256, 0, stream>>>(X, Wq, Wk, Wv, Wo, wsb);
    k_rowstats<<<dim3(NA, 2),     256, 0, stream>>>(f_dist, f_clb, wsb);
    k_proj    <<<dim3(8, 32, 3),  256, 0, stream>>>(wsb);
    k_transKV <<<dim3(16, 64, 2), 256, 0, stream>>>(wsb);
    k_ktv     <<<dim3(16, 8),     256, 0, stream>>>(wsb);
    k_m2cvt   <<<64,              256, 0, stream>>>(wsb);
    k_scores  <<<dim3(32, 32),    256, 0, stream>>>(wsb, f_adj, f_dist, f_clb,
                                                    out_scores, c_scale/8.f, c_scale/4.f);
    // RETF aliases KB (read by k_scores) -> zero it only after k_scores
    hipMemsetAsync(wsb + OFF_RETF, 0, (size_t)NA * 768 * 4, stream);
    k_ret2    <<<dim3(4, 32, 3),  512, 0, stream>>>(wsb, f_adj, f_dist, f_clb);
    k_retfin  <<<dim3(8, 32),     256, 0, stream>>>(wsb, c_scale);
    k_wo      <<<dim3(8, 32),     256, 0, stream>>>(wsb, X, bo);
    k_ln      <<<NA,              256, 0, stream>>>(wsb, ln_g, ln_b, out);
}

// Round 6
// 544.767 us; speedup vs baseline: 3.6613x; 1.0125x over previous
//
#include <hip/hip_runtime.h>
#include <math.h>

#define NA     4096
#define HID    1024
#define LN_EPS 1e-5f

typedef short s8   __attribute__((ext_vector_type(8)));
typedef float f32x4 __attribute__((ext_vector_type(4)));

// ---- workspace layout (BYTE offsets), peak ~57 MB ----
#define OFF_XBF   ((size_t)0)              // [4096][1024] bf16, 8 MB (dead after k_proj)
#define OFF_WQT   ((size_t)8<<20)          // 2 MB each (dead after k_proj)
#define OFF_WKT   ((size_t)10<<20)
#define OFF_WVT   ((size_t)12<<20)
#define OFF_QB    ((size_t)14<<20)         // 8 MB (dead after k_retfin)
#define OFF_KB    ((size_t)22<<20)         // 8 MB (dead after k_scores)
#define OFF_VB    ((size_t)30<<20)         // 8 MB (dead after k_transKV)
#define OFF_KT    ((size_t)38<<20)         // 8 MB (dead after k_ktv)
#define OFF_VT    ((size_t)46<<20)         // 8 MB (dead after k_ret2)
#define OFF_WOT   ((size_t)54<<20)         // 2 MB (dead after k_wo)
#define OFF_M2F   ((size_t)56<<20)         // fp32 [8][128][128], 512 KB
#define OFF_M2B   (OFF_M2F + ((size_t)512<<10))
#define OFF_RMAXD (OFF_M2F + ((size_t)768<<10))
#define OFF_RINVD (OFF_RMAXD + 16384)
#define OFF_RMAXC (OFF_RINVD + 16384)
#define OFF_RINVC (OFF_RMAXC + 16384)
#define OFF_RETF  ((size_t)22<<20)         // fp32 [4096][768], 12 MB; aliases KB + VB[0:4M]
#define OFF_RETB  ((size_t)34<<20)         // bf16 [4096][1024], 8 MB; aliases VB[4:8M] + KT[0:4M]
#define OFF_YF    ((size_t)0)              // fp32 [4096][1024], 16 MB; aliases XBF..QB[0:2M]

__device__ __forceinline__ ushort f2bf(float f) {   // RNE fp32->bf16
    unsigned u = __float_as_uint(f);
    u += 0x7FFFu + ((u >> 16) & 1u);
    return (ushort)(u >> 16);
}

// async 16B global->LDS (HW: per-lane global addr, wave-uniform LDS base + lane*16)
__device__ __forceinline__ void gl16(const void* g, void* l) {
    __builtin_amdgcn_global_load_lds(
        (const __attribute__((address_space(1))) void*)g,
        (__attribute__((address_space(3))) void*)l, 16, 0, 0);
}

// 16 MFMAs on staged [*][32]-linear bf16 tiles; wave (wr,wc) owns 64x64.
__device__ __forceinline__ void mfma_tile(const short* As, const short* Bs,
                                          f32x4 (&acc)[4][4], int lane, int wr, int wc)
{
    const int r = lane & 15, kg = (lane >> 4) * 8;
    s8 a[4], b[4];
#pragma unroll
    for (int i = 0; i < 4; i++) a[i] = *(const s8*)&As[(wr*64 + i*16 + r)*32 + kg];
#pragma unroll
    for (int j = 0; j < 4; j++) b[j] = *(const s8*)&Bs[(wc*64 + j*16 + r)*32 + kg];
#pragma unroll
    for (int i = 0; i < 4; i++)
#pragma unroll
        for (int j = 0; j < 4; j++)
            acc[i][j] = __builtin_amdgcn_mfma_f32_16x16x32_bf16(a[i], b[j], acc[i][j], 0, 0, 0);
}

// async NT GEMM (256 thr, 4 waves 2x2): C128x128 at (row0,col0) = sum_k A[m][k]*Bt[n][k]
// LDS tiles linear [128][32] shorts; staged via global_load_lds width-16.
__device__ __forceinline__ void gemm_bf16_nt_async(const ushort* A, int lda,
    const ushort* Bt, int ldb, int K, int row0, int col0,
    short* As, short* Bs, f32x4 (&acc)[4][4], int tid)
{
    const int lane = tid & 63, wave = tid >> 6, wr = wave >> 1, wc = wave & 1;
    // wave stages rows [wave*32, wave*32+32): two 16-row chunks; lane -> row +(l>>2), col (l&3)*8
    const int srow = wave*32 + (lane >> 2), scol = (lane & 3) * 8;
    const ushort* Ap0 = A  + (size_t)(row0 + srow) * lda + scol;
    const ushort* Ap1 = Ap0 + 16 * (size_t)lda;
    const ushort* Bp0 = Bt + (size_t)(col0 + srow) * ldb + scol;
    const ushort* Bp1 = Bp0 + 16 * (size_t)ldb;
    short* As0 = As + (wave*32)*32;      // wave-uniform LDS bases (lane*16B appended by HW)
    short* As1 = As + (wave*32+16)*32;
    short* Bs0 = Bs + (wave*32)*32;
    short* Bs1 = Bs + (wave*32+16)*32;
    for (int kt = 0; kt < K; kt += 32) {
        __syncthreads();                 // prev MFMA ds_reads complete
        gl16(Ap0 + kt, As0);
        gl16(Ap1 + kt, As1);
        gl16(Bp0 + kt, Bs0);
        gl16(Bp1 + kt, Bs1);
        __syncthreads();                 // drains vmcnt -> tiles resident
        mfma_tile(As, Bs, acc, lane, wr, wc);
    }
}

#define ZERO_ACC(acc) { f32x4 z = {0.f,0.f,0.f,0.f}; \
    _Pragma("unroll") for (int i=0;i<4;i++) _Pragma("unroll") for (int j=0;j<4;j++) acc[i][j]=z; }

// =====================================================================
// prep: z=0 X->bf16 ; z=1..4 transpose+convert Wq/Wk/Wv/Wo
// =====================================================================
__global__ __launch_bounds__(256) void k_prep(const float* __restrict__ X,
    const float* __restrict__ Wq, const float* __restrict__ Wk,
    const float* __restrict__ Wv, const float* __restrict__ Wo, char* __restrict__ wsb)
{
    const int z = blockIdx.z, bx = blockIdx.x, by = blockIdx.y, t = threadIdx.x;
    const int lr = t >> 2, jb = t & 3;
    if (z == 0) {
        const float* src = X + (size_t)(by*64 + lr) * HID + bx*64 + jb*16;
        ushort* dst = (ushort*)(wsb + OFF_XBF) + (size_t)(by*64 + lr) * HID + bx*64 + jb*16;
        union { ushort u[16]; uint4 q[2]; } pk;
        union { float f[16]; float4 v[4]; } fa;
#pragma unroll
        for (int m = 0; m < 4; m++) fa.v[m] = ((const float4*)src)[m];
#pragma unroll
        for (int m = 0; m < 16; m++) pk.u[m] = f2bf(fa.f[m]);
        ((uint4*)dst)[0] = pk.q[0]; ((uint4*)dst)[1] = pk.q[1];
        return;
    }
    if (by >= 16) return;
    __shared__ ushort Tl[64][72];
    const float* W = (z == 1) ? Wq : (z == 2) ? Wk : (z == 3) ? Wv : Wo;
    ushort* WT = (ushort*)(wsb + ((z==1)?OFF_WQT:(z==2)?OFF_WKT:(z==3)?OFF_WVT:OFF_WOT));
    const int r0 = by*64, c0 = bx*64;
    const float* src = W + (size_t)(r0 + lr) * HID + c0 + jb*16;
    union { float f[16]; float4 v[4]; } fa;
#pragma unroll
    for (int m = 0; m < 4; m++) fa.v[m] = ((const float4*)src)[m];
#pragma unroll
    for (int m = 0; m < 16; m++) Tl[lr][jb*16 + m] = f2bf(fa.f[m]);
    __syncthreads();
    union { ushort u[16]; uint4 q[2]; } pk;
#pragma unroll
    for (int m = 0; m < 16; m++) pk.u[m] = Tl[jb*16 + m][lr];
    ushort* dst = WT + (size_t)(c0 + lr) * HID + r0 + jb*16;
    ((uint4*)dst)[0] = pk.q[0]; ((uint4*)dst)[1] = pk.q[1];
}

// =====================================================================
// Row softmax stats for f_dist / f_clb
// =====================================================================
__global__ __launch_bounds__(256) void k_rowstats(const float* __restrict__ f_dist,
    const float* __restrict__ f_clb, char* __restrict__ wsb)
{
    const int row = blockIdx.x, mat = blockIdx.y, t = threadIdx.x;
    const float* F = mat ? f_clb : f_dist;
    float* rmax = (float*)(wsb + (mat ? OFF_RMAXC : OFF_RMAXD));
    float* rinv = (float*)(wsb + (mat ? OFF_RINVC : OFF_RINVD));
    float4 v[4];
#pragma unroll
    for (int p = 0; p < 4; p++)
        v[p] = *(const float4*)(F + (size_t)row * NA + 4*t + 1024*p);
    float m = -1e30f;
#pragma unroll
    for (int p = 0; p < 4; p++)
        m = fmaxf(m, fmaxf(fmaxf(v[p].x, v[p].y), fmaxf(v[p].z, v[p].w)));
    for (int off = 32; off; off >>= 1) m = fmaxf(m, __shfl_xor(m, off));
    __shared__ float sb[4];
    if ((t & 63) == 0) sb[t >> 6] = m;
    __syncthreads();
    const float m4 = fmaxf(fmaxf(sb[0], sb[1]), fmaxf(sb[2], sb[3]));
    __syncthreads();
    float s = 0.f;
#pragma unroll
    for (int p = 0; p < 4; p++)
        s += expf(v[p].x-m4) + expf(v[p].y-m4) + expf(v[p].z-m4) + expf(v[p].w-m4);
    for (int off = 32; off; off >>= 1) s += __shfl_xor(s, off);
    if ((t & 63) == 0) sb[t >> 6] = s;
    __syncthreads();
    if (t == 0) { rmax[row] = m4; rinv[row] = 1.0f / (sb[0]+sb[1]+sb[2]+sb[3]); }
}

// =====================================================================
// proj: {Q,K,V}b = Xbf @ W{q,k,v}T^T
// =====================================================================
__global__ __launch_bounds__(256) void k_proj(char* __restrict__ wsb)
{
    __shared__ __align__(16) short As[128*32], Bs[128*32];
    const int z = blockIdx.z;
    const ushort* A  = (const ushort*)(wsb + OFF_XBF);
    const ushort* Bt = (const ushort*)(wsb + ((z==0)?OFF_WQT:(z==1)?OFF_WKT:OFF_WVT));
    ushort* O = (ushort*)(wsb + ((z==0)?OFF_QB:(z==1)?OFF_KB:OFF_VB));
    const int row0 = blockIdx.y*128, col0 = blockIdx.x*128;
    f32x4 acc[4][4]; ZERO_ACC(acc);
    gemm_bf16_nt_async(A, HID, Bt, HID, HID, row0, col0, As, Bs, acc, threadIdx.x);
    const int lane = threadIdx.x & 63, wave = threadIdx.x >> 6, wr = wave>>1, wc = wave&1;
#pragma unroll
    for (int i = 0; i < 4; i++)
#pragma unroll
    for (int e = 0; e < 4; e++) {
        const int r = row0 + wr*64 + i*16 + (lane>>4)*4 + e;
#pragma unroll
        for (int j = 0; j < 4; j++) {
            const int c = col0 + wc*64 + j*16 + (lane & 15);
            O[(size_t)r*HID + c] = f2bf(acc[i][j][e]);
        }
    }
}

// =====================================================================
// transKV: z=0 Kb->KT, z=1 Vb->VT
// =====================================================================
__global__ __launch_bounds__(256) void k_transKV(char* __restrict__ wsb)
{
    const int z = blockIdx.z;
    const ushort* in = (const ushort*)(wsb + (z ? OFF_VB : OFF_KB));
    ushort* out = (ushort*)(wsb + (z ? OFF_VT : OFF_KT));
    const int n0 = blockIdx.y*64, c0 = blockIdx.x*64;
    const int t = threadIdx.x, lr = t >> 2, jb = t & 3;
    __shared__ ushort Tl[64][72];
    const ushort* src = in + (size_t)(n0 + lr) * HID + c0 + jb*16;
    union { ushort u[16]; uint4 q[2]; } pk;
    pk.q[0] = ((const uint4*)src)[0]; pk.q[1] = ((const uint4*)src)[1];
#pragma unroll
    for (int m = 0; m < 16; m++) Tl[lr][jb*16 + m] = pk.u[m];
    __syncthreads();
#pragma unroll
    for (int m = 0; m < 16; m++) pk.u[m] = Tl[jb*16 + m][lr];
    ushort* dst = out + (size_t)(c0 + lr) * NA + n0 + jb*16;
    ((uint4*)dst)[0] = pk.q[0]; ((uint4*)dst)[1] = pk.q[1];
}

// =====================================================================
// ktv: M2[h] = M_h^T = (VT_h)(KT_h)^T, split over 16 n-chunks, atomicAdd fp32
// =====================================================================
__global__ __launch_bounds__(256) void k_ktv(char* __restrict__ wsb)
{
    __shared__ __align__(16) short As[128*32], Bs[128*32];
    const int ci = blockIdx.x, h = blockIdx.y;
    const ushort* A  = (const ushort*)(wsb + OFF_VT) + (size_t)h*128*NA + ci*256;
    const ushort* Bt = (const ushort*)(wsb + OFF_KT) + (size_t)h*128*NA + ci*256;
    f32x4 acc[4][4]; ZERO_ACC(acc);
    gemm_bf16_nt_async(A, NA, Bt, NA, 256, 0, 0, As, Bs, acc, threadIdx.x);
    float* M2f = (float*)(wsb + OFF_M2F) + (size_t)h*16384;
    const int lane = threadIdx.x & 63, wave = threadIdx.x >> 6, wr = wave>>1, wc = wave&1;
#pragma unroll
    for (int i = 0; i < 4; i++)
#pragma unroll
    for (int e = 0; e < 4; e++) {
        const int r = wr*64 + i*16 + (lane>>4)*4 + e;
#pragma unroll
        for (int j = 0; j < 4; j++) {
            const int c = wc*64 + j*16 + (lane & 15);
            atomicAdd(&M2f[r*128 + c], acc[i][j][e]);
        }
    }
}

__global__ __launch_bounds__(256) void k_m2cvt(char* __restrict__ wsb)
{
    const int i = (blockIdx.x*256 + threadIdx.x) * 8;
    const float* s = (const float*)(wsb + OFF_M2F);
    ushort* d = (ushort*)(wsb + OFF_M2B);
    union { float f[8]; float4 v[2]; } fa;
    fa.v[0] = *(const float4*)(s + i); fa.v[1] = *(const float4*)(s + i + 4);
    union { ushort u[8]; uint4 q; } pk;
#pragma unroll
    for (int m = 0; m < 8; m++) pk.u[m] = f2bf(fa.f[m]);
    *(uint4*)(d + i) = pk.q;
}

// =====================================================================
// scores: out = c/8 * Qb@Kb^T + c/4 * (adj + softmax(fd) + softmax(fc))
// XCD-aware bijective swizzle (nwg=1024, 1024%8==0).
// =====================================================================
__global__ __launch_bounds__(256) void k_scores(char* __restrict__ wsb,
    const float* __restrict__ f_adj, const float* __restrict__ f_dist,
    const float* __restrict__ f_clb, float* __restrict__ outs, float cdiv8, float cdiv4)
{
    __shared__ __align__(16) short As[128*32], Bs[128*32];
    const int lin = blockIdx.y*32 + blockIdx.x;
    const int sw  = (lin & 7)*128 + (lin >> 3);     // XCD chunked swizzle
    const int row0 = (sw >> 5)*128, col0 = (sw & 31)*128;
    f32x4 acc[4][4]; ZERO_ACC(acc);
    gemm_bf16_nt_async((const ushort*)(wsb + OFF_QB), HID,
                       (const ushort*)(wsb + OFF_KB), HID, HID, row0, col0,
                       As, Bs, acc, threadIdx.x);
    const float* rmaxd = (const float*)(wsb + OFF_RMAXD);
    const float* rinvd = (const float*)(wsb + OFF_RINVD);
    const float* rmaxc = (const float*)(wsb + OFF_RMAXC);
    const float* rinvc = (const float*)(wsb + OFF_RINVC);
    const int lane = threadIdx.x & 63, wave = threadIdx.x >> 6, wr = wave>>1, wc = wave&1;
#pragma unroll
    for (int i = 0; i < 4; i++)
#pragma unroll
    for (int e = 0; e < 4; e++) {
        const int r = row0 + wr*64 + i*16 + (lane>>4)*4 + e;
        const float rmd = rmaxd[r], rid = rinvd[r], rmc = rmaxc[r], ric = rinvc[r];
#pragma unroll
        for (int j = 0; j < 4; j++) {
            const int c = col0 + wc*64 + j*16 + (lane & 15);
            const size_t idx = (size_t)r * NA + c;
            const float bias = f_adj[idx] + __expf(f_dist[idx]-rmd)*rid
                                          + __expf(f_clb[idx]-rmc)*ric;
            outs[idx] = cdiv8 * acc[i][j][e] + cdiv4 * bias;
        }
    }
}

// =====================================================================
// ret2: RETF[:, p*256..+256) += B_p @ [v_2p | v_2p+1]  (merged head pair,
//       split-K x4, fp32 atomic accum). A reg-staged (fused exp/cvt),
//       B via global_load_lds.
// =====================================================================
__global__ __launch_bounds__(512, 2) void k_ret2(char* __restrict__ wsb,
    const float* __restrict__ f_adj, const float* __restrict__ f_dist,
    const float* __restrict__ f_clb)
{
    __shared__ __align__(16) short As[128*32];
    __shared__ __align__(16) short Bs[256*32];
    const int kc = blockIdx.x;            // K chunk 0..3 (1024 each)
    const int row0 = blockIdx.y * 128;
    const int p = blockIdx.z;             // pair 0..2
    const int tid = threadIdx.x, lane = tid & 63, wave = tid >> 6;
    const int wr = wave >> 2, wc = wave & 3;      // 2 x 4 waves over 128x256
    const int ar = tid >> 2, ac = (tid & 3) * 8;  // A reg-stage: 128 rows x 32
    const int srow = wave*32 + (lane >> 2), scol = (lane & 3) * 8;  // B async rows

    const float* F = (p == 0) ? f_adj : (p == 1) ? f_dist : f_clb;
    float rm = 0.f, ri = 1.f;
    if (p) {
        rm = ((const float*)(wsb + ((p==1) ? OFF_RMAXD : OFF_RMAXC)))[row0 + ar];
        ri = ((const float*)(wsb + ((p==1) ? OFF_RINVD : OFF_RINVC)))[row0 + ar];
    }
    const float*  Fp  = F + (size_t)(row0 + ar) * NA + kc*1024 + ac;
    const ushort* Bp0 = (const ushort*)(wsb + OFF_VT) + (size_t)(p*256 + srow) * NA + kc*1024 + scol;
    const ushort* Bp1 = Bp0 + 16 * (size_t)NA;
    short* Ad  = &As[ar * 32 + ac];
    short* Bs0 = &Bs[(wave*32)*32];
    short* Bs1 = &Bs[(wave*32+16)*32];

    f32x4 acc[4][4]; ZERO_ACC(acc);
    for (int kt = 0; kt < 1024; kt += 32) {
        union { float f[8]; float4 v[2]; } fa;     // A loads issue pre-barrier (overlap prev MFMA)
        fa.v[0] = *(const float4*)(Fp + kt);
        fa.v[1] = *(const float4*)(Fp + kt + 4);
        if (p) {
#pragma unroll
            for (int m = 0; m < 8; m++) fa.f[m] = __expf(fa.f[m] - rm) * ri;
        }
        union { ushort u[8]; uint4 q; } pk;
#pragma unroll
        for (int m = 0; m < 8; m++) pk.u[m] = f2bf(fa.f[m]);
        __syncthreads();
        gl16(Bp0 + kt, Bs0);
        gl16(Bp1 + kt, Bs1);
        *(uint4*)Ad = pk.q;
        __syncthreads();
        mfma_tile(As, Bs, acc, lane, wr, wc);
    }
    float* RF = (float*)(wsb + OFF_RETF);
#pragma unroll
    for (int i = 0; i < 4; i++)
#pragma unroll
    for (int e = 0; e < 4; e++) {
        const int r = row0 + wr*64 + i*16 + (lane>>4)*4 + e;
#pragma unroll
        for (int j = 0; j < 4; j++) {
            const int c = p*256 + wc*64 + j*16 + (lane & 15);
            atomicAdd(&RF[(size_t)r * 768 + c], acc[i][j][e]);
        }
    }
}

// =====================================================================
// retfin: RETB = relu(c * (q_h @ M_h + RETF[bias part])), bf16 out
// =====================================================================
__global__ __launch_bounds__(256) void k_retfin(char* __restrict__ wsb, float c_scale)
{
    __shared__ __align__(16) short As[128*32], Bs[128*32];
    const int h = blockIdx.x, row0 = blockIdx.y * 128;
    const ushort* A  = (const ushort*)(wsb + OFF_QB) + (size_t)row0 * HID + h*128;
    const ushort* Bt = (const ushort*)(wsb + OFF_M2B) + (size_t)h * 16384;
    f32x4 acc[4][4]; ZERO_ACC(acc);
    gemm_bf16_nt_async(A, HID, Bt, 128, 128, 0, 0, As, Bs, acc, threadIdx.x);
    const float* RF = (const float*)(wsb + OFF_RETF);
    ushort* RB = (ushort*)(wsb + OFF_RETB);
    const int lane = threadIdx.x & 63, wave = threadIdx.x >> 6, wr = wave>>1, wc = wave&1;
#pragma unroll
    for (int i = 0; i < 4; i++)
#pragma unroll
    for (int e = 0; e < 4; e++) {
        const int r = row0 + wr*64 + i*16 + (lane>>4)*4 + e;
#pragma unroll
        for (int j = 0; j < 4; j++) {
            const int cl = wc*64 + j*16 + (lane & 15);
            const int col = h*128 + cl;
            float v = acc[i][j][e];
            if (h < 6) v += RF[(size_t)r * 768 + col];
            RB[(size_t)r * HID + col] = f2bf(fmaxf(c_scale * v, 0.f));
        }
    }
}

// =====================================================================
// wo: Yf = X + RETB @ WoT^T + bo
// =====================================================================
__global__ __launch_bounds__(256) void k_wo(char* __restrict__ wsb,
    const float* __restrict__ X, const float* __restrict__ bo)
{
    __shared__ __align__(16) short As[128*32], Bs[128*32];
    const int row0 = blockIdx.y*128, col0 = blockIdx.x*128;
    f32x4 acc[4][4]; ZERO_ACC(acc);
    gemm_bf16_nt_async((const ushort*)(wsb + OFF_RETB), HID,
                       (const ushort*)(wsb + OFF_WOT), HID, HID, row0, col0,
                       As, Bs, acc, threadIdx.x);
    float* Y = (float*)(wsb + OFF_YF);
    const int lane = threadIdx.x & 63, wave = threadIdx.x >> 6, wr = wave>>1, wc = wave&1;
#pragma unroll
    for (int i = 0; i < 4; i++)
#pragma unroll
    for (int e = 0; e < 4; e++) {
        const int r = row0 + wr*64 + i*16 + (lane>>4)*4 + e;
#pragma unroll
        for (int j = 0; j < 4; j++) {
            const int c = col0 + wc*64 + j*16 + (lane & 15);
            Y[(size_t)r*HID + c] = acc[i][j][e] + X[(size_t)r*HID + c] + bo[c];
        }
    }
}

// =====================================================================
// LayerNorm rows of Yf -> mol_vec
// =====================================================================
__global__ __launch_bounds__(256) void k_ln(const char* __restrict__ wsb,
    const float* __restrict__ g, const float* __restrict__ b, float* __restrict__ out)
{
    const float* Y = (const float*)(wsb + OFF_YF);
    const int row = blockIdx.x, t = threadIdx.x;
    float4 v = *(const float4*)(Y + (size_t)row * HID + 4*t);
    float s = v.x + v.y + v.z + v.w;
    for (int off = 32; off; off >>= 1) s += __shfl_xor(s, off);
    __shared__ float sb[4];
    if ((t & 63) == 0) sb[t >> 6] = s;
    __syncthreads();
    const float mu = (sb[0]+sb[1]+sb[2]+sb[3]) * (1.0f / HID);
    const float dx = v.x-mu, dy = v.y-mu, dz = v.z-mu, dw = v.w-mu;
    float q = dx*dx + dy*dy + dz*dz + dw*dw;
    __syncthreads();
    for (int off = 32; off; off >>= 1) q += __shfl_xor(q, off);
    if ((t & 63) == 0) sb[t >> 6] = q;
    __syncthreads();
    const float var = (sb[0]+sb[1]+sb[2]+sb[3]) * (1.0f / HID);
    const float rstd = rsqrtf(var + LN_EPS);
    float4 gv = *(const float4*)(g + 4*t);
    float4 bv = *(const float4*)(b + 4*t);
    float4 o = make_float4(dx*rstd*gv.x + bv.x, dy*rstd*gv.y + bv.y,
                           dz*rstd*gv.z + bv.z, dw*rstd*gv.w + bv.w);
    *(float4*)(out + (size_t)row * HID + 4*t) = o;
}

// =====================================================================
extern "C" void kernel_launch(void* const* d_in, const int* in_sizes, int n_in,
                              void* d_out, int out_size, void* d_ws, size_t ws_size,
                              hipStream_t stream)
{
    const float* X      = (const float*)d_in[0];
    const float* f_adj  = (const float*)d_in[1];
    const float* f_dist = (const float*)d_in[2];
    const float* f_clb  = (const float*)d_in[3];
    const float* Wq     = (const float*)d_in[4];
    const float* Wk     = (const float*)d_in[5];
    const float* Wv     = (const float*)d_in[6];
    const float* Wo     = (const float*)d_in[7];
    const float* bo     = (const float*)d_in[8];
    const float* ln_g   = (const float*)d_in[9];
    const float* ln_b   = (const float*)d_in[10];

    char* wsb = (char*)d_ws;
    float* out = (float*)d_out;
    float* out_scores = out + (size_t)NA * HID;

    const float c_scale = (float)pow(1.0 - 1.0/32.0, 1.0 / sqrt(128.0));

    hipMemsetAsync(wsb + OFF_M2F, 0, (size_t)512 << 10, stream);

    k_prep    <<<dim3(16, 64, 5), 256, 0, stream>>>(X, Wq, Wk, Wv, Wo, wsb);
    k_rowstats<<<dim3(NA, 2),     256, 0, stream>>>(f_dist, f_clb, wsb);
    k_proj    <<<dim3(8, 32, 3),  256, 0, stream>>>(wsb);
    k_transKV <<<dim3(16, 64, 2), 256, 0, stream>>>(wsb);
    k_ktv     <<<dim3(16, 8),     256, 0, stream>>>(wsb);
    k_m2cvt   <<<64,              256, 0, stream>>>(wsb);
    k_scores  <<<dim3(32, 32),    256, 0, stream>>>(wsb, f_adj, f_dist, f_clb,
                                                    out_scores, c_scale/8.f, c_scale/4.f);
    // RETF aliases KB (read by k_scores) -> zero it only after k_scores
    hipMemsetAsync(wsb + OFF_RETF, 0, (size_t)NA * 768 * 4, stream);
    k_ret2    <<<dim3(4, 32, 3),  512, 0, stream>>>(wsb, f_adj, f_dist, f_clb);
    k_retfin  <<<dim3(8, 32),     256, 0, stream>>>(wsb, c_scale);
    k_wo      <<<dim3(8, 32),     256, 0, stream>>>(wsb, X, bo);
    k_ln      <<<NA,              256, 0, stream>>>(wsb, ln_g, ln_b, out);
}